// Round 6
// baseline (865.347 us; speedup 1.0000x reference)
//
#include <hip/hip_runtime.h>
#include <hip/hip_bf16.h>
#include <cstdint>
#include <cstddef>

#define N_NODES   100000
#define N_EDGES   1600000
#define N_GRAPHS  64
#define HIDDEN    256
#define N_CLASSES 10
#define NEG_SLOPE 0.01f

typedef __attribute__((ext_vector_type(8))) short bfrag8;   // 8 bf16 (4 VGPRs)
typedef __attribute__((ext_vector_type(4))) float f32x4;    // MFMA C/D

__device__ __forceinline__ float bf2f(unsigned short u) {
    return __uint_as_float(((unsigned int)u) << 16);
}

// ---------------- degree histogram (4 edges/thread, 4 atomics in flight) ----------------
__global__ void k_deg_hist(const int* __restrict__ dst, int* __restrict__ cnt) {
    int e = (blockIdx.x * 256 + threadIdx.x) * 4;
    if (e >= N_EDGES) return;
    int4 d4 = *(const int4*)(dst + e);
    atomicAdd(&cnt[d4.x], 1);
    atomicAdd(&cnt[d4.y], 1);
    atomicAdd(&cnt[d4.z], 1);
    atomicAdd(&cnt[d4.w], 1);
}

// ---------------- graph boundaries via binary search (batch is sorted) ----------------
__global__ void k_graph_bounds(const int* __restrict__ batch,
                               int* __restrict__ gstart, int* __restrict__ gcnt) {
    int g = threadIdx.x;  // 0..63
    int lo = 0, hi = N_NODES;
    while (lo < hi) { int mid = (lo + hi) >> 1; if (batch[mid] < g) lo = mid + 1; else hi = mid; }
    __shared__ int sh[N_GRAPHS + 1];
    sh[g] = lo;
    if (g == 0) sh[N_GRAPHS] = N_NODES;
    __syncthreads();
    gstart[g] = sh[g];
    gcnt[g]   = sh[g + 1] - sh[g];
}

__global__ void k_dinv(const int* __restrict__ cnt, float* __restrict__ dinv) {
    int i = blockIdx.x * 256 + threadIdx.x;
    if (i < N_NODES) dinv[i] = rsqrtf((float)cnt[i] + 1.0f);
}

// ---------------- exclusive scan of PADDED degree counts (CSR offsets) ----------------
// degrees rounded up to multiple of 4 so the agg loop is exact int4-wide
__global__ void k_scanA(const int* __restrict__ cnt, int* __restrict__ out, int* __restrict__ bsum) {
    __shared__ int sh[256];
    int tid = threadIdx.x;
    int base = blockIdx.x * 1024 + tid * 4;
    int v[4]; int s = 0;
#pragma unroll
    for (int i = 0; i < 4; i++) {
        int idx = base + i;
        v[i] = (idx < N_NODES) ? ((cnt[idx] + 3) & ~3) : 0;
        s += v[i];
    }
    sh[tid] = s; __syncthreads();
    for (int off = 1; off < 256; off <<= 1) {
        int t = (tid >= off) ? sh[tid - off] : 0;
        __syncthreads();
        sh[tid] += t;
        __syncthreads();
    }
    int excl = sh[tid] - s;
    if (tid == 255) bsum[blockIdx.x] = sh[255];
#pragma unroll
    for (int i = 0; i < 4; i++) { int idx = base + i; if (idx < N_NODES) out[idx] = excl; excl += v[i]; }
}

__global__ void k_scanB(int* __restrict__ bsum, int nb) {
    __shared__ int sh[128];
    int tid = threadIdx.x;
    int v = (tid < nb) ? bsum[tid] : 0;
    sh[tid] = v; __syncthreads();
    for (int off = 1; off < 128; off <<= 1) {
        int t = (tid >= off) ? sh[tid - off] : 0;
        __syncthreads();
        sh[tid] += t;
        __syncthreads();
    }
    if (tid < nb) bsum[tid] = sh[tid] - v;  // exclusive
}

// finalize offsets + init cursor + write -1 sentinels into padding slots
__global__ void k_scanC(int* __restrict__ off_arr, const int* __restrict__ bsum,
                        int* __restrict__ cursor, const int* __restrict__ cnt,
                        int* __restrict__ csrc) {
    int i = blockIdx.x * 256 + threadIdx.x;
    if (i < N_NODES) {
        int v = off_arr[i] + bsum[i >> 10];
        off_arr[i] = v;
        cursor[i]  = v;
        int c  = cnt[i];
        int cp = (c + 3) & ~3;
        for (int p = v + c; p < v + cp; ++p) csrc[p] = -1;
        if (i == N_NODES - 1) off_arr[N_NODES] = v + cp;
    }
}

// ---------------- CSR fill (sorted by dst), 4 edges/thread ----------------
__global__ void k_fill(const int* __restrict__ src, const int* __restrict__ dst,
                       int* __restrict__ cursor, int* __restrict__ csrc) {
    int e = (blockIdx.x * 256 + threadIdx.x) * 4;
    if (e >= N_EDGES) return;
    int4 d4 = *(const int4*)(dst + e);
    int4 s4 = *(const int4*)(src + e);
    int p0 = atomicAdd(&cursor[d4.x], 1);
    int p1 = atomicAdd(&cursor[d4.y], 1);
    int p2 = atomicAdd(&cursor[d4.z], 1);
    int p3 = atomicAdd(&cursor[d4.w], 1);
    csrc[p0] = s4.x; csrc[p1] = s4.y; csrc[p2] = s4.z; csrc[p3] = s4.w;
}

// ---------------- weight prep: W[k][n] fp32 -> Wt[n][k] bf16 ----------------
__global__ void k_wprep(const float* __restrict__ W, __hip_bfloat16* __restrict__ Wt) {
    int n = blockIdx.x; int k = threadIdx.x;  // 256 x 256
    Wt[n * HIDDEN + k] = __float2bfloat16(W[k * HIDDEN + n]);
}

// ---------------- layer-1 reassociated: ax = Norm * x  (3 features, exact) ----------------
__global__ void k_agg3(const float* __restrict__ x, const int* __restrict__ off,
                       const int* __restrict__ csrc, const float* __restrict__ dinv,
                       float4* __restrict__ ax) {
    int i = blockIdx.x * 256 + threadIdx.x;
    if (i >= N_NODES) return;
    float di = dinv[i];
    float selfc = di * di;
    float a0 = x[i * 3 + 0] * selfc, a1 = x[i * 3 + 1] * selfc, a2 = x[i * 3 + 2] * selfc;
    int e = off[i], e1 = off[i + 1];
    for (; e < e1; e += 4) {
        int4 ss = *(const int4*)(csrc + e);
        int s0 = ss.x >= 0 ? ss.x : 0, s1 = ss.y >= 0 ? ss.y : 0;
        int s2 = ss.z >= 0 ? ss.z : 0, s3 = ss.w >= 0 ? ss.w : 0;
        float c0 = ss.x >= 0 ? dinv[s0] * di : 0.f;
        float c1 = ss.y >= 0 ? dinv[s1] * di : 0.f;
        float c2 = ss.z >= 0 ? dinv[s2] * di : 0.f;
        float c3 = ss.w >= 0 ? dinv[s3] * di : 0.f;
        a0 += c0 * x[s0 * 3 + 0] + c1 * x[s1 * 3 + 0] + c2 * x[s2 * 3 + 0] + c3 * x[s3 * 3 + 0];
        a1 += c0 * x[s0 * 3 + 1] + c1 * x[s1 * 3 + 1] + c2 * x[s2 * 3 + 1] + c3 * x[s3 * 3 + 1];
        a2 += c0 * x[s0 * 3 + 2] + c1 * x[s1 * 3 + 2] + c2 * x[s2 * 3 + 2] + c3 * x[s3 * 3 + 2];
    }
    ax[i] = make_float4(a0, a1, a2, 0.f);
}

// h1 = leaky(ax @ W1 + b1), bf16 out
__global__ void k_l1(const float4* __restrict__ ax, const float* __restrict__ W1,
                     const float* __restrict__ b1, __hip_bfloat16* __restrict__ out) {
    int node = blockIdx.x; int c = threadIdx.x;
    float4 a = ax[node];
    float v = a.x * W1[c] + a.y * W1[HIDDEN + c] + a.z * W1[2 * HIDDEN + c] + b1[c];
    v = v >= 0.f ? v : NEG_SLOPE * v;
    out[(size_t)node * HIDDEN + c] = __float2bfloat16(v);
}

// ---------------- MFMA GEMM with LDS-staged Wt ----------------
__global__ __launch_bounds__(256) void k_gemm_mfma(const __hip_bfloat16* __restrict__ A,
                                                   const __hip_bfloat16* __restrict__ Wt,
                                                   __hip_bfloat16* __restrict__ C, int M) {
    __shared__ short Bs[256 * 40];  // 20 KB
    int tid = threadIdx.x;
    int wv = tid >> 6, lane = tid & 63;
    int quad = lane >> 4, r = lane & 15;
    int m0 = blockIdx.x * 64 + wv * 16;
    int arow = m0 + r; if (arow >= M) arow = M - 1;
    const short* Ab = (const short*)A + (size_t)arow * HIDDEN + quad * 8;

    bfrag8 af[8];
#pragma unroll
    for (int c = 0; c < 8; ++c) af[c] = *(const bfrag8*)(Ab + c * 32);

    f32x4 acc[16];
#pragma unroll
    for (int i = 0; i < 16; i++) acc[i] = (f32x4){0.f, 0.f, 0.f, 0.f};

    const float4* wsrc = (const float4*)((const short*)Wt + (size_t)tid * HIDDEN);  // row n=tid
    float4 st[4];
#pragma unroll
    for (int i = 0; i < 4; ++i) st[i] = wsrc[i];  // chunk 0

#pragma unroll
    for (int c = 0; c < 8; ++c) {
        __syncthreads();
        float4* bdst = (float4*)(Bs + tid * 40);
#pragma unroll
        for (int i = 0; i < 4; ++i) bdst[i] = st[i];
        __syncthreads();
        if (c < 7) {
#pragma unroll
            for (int i = 0; i < 4; ++i) st[i] = wsrc[(c + 1) * 4 + i];
        }
#pragma unroll
        for (int nt = 0; nt < 16; ++nt) {
            bfrag8 b = *(const bfrag8*)(Bs + (nt * 16 + r) * 40 + quad * 8);
            acc[nt] = __builtin_amdgcn_mfma_f32_16x16x32_bf16(af[c], b, acc[nt], 0, 0, 0);
        }
    }
#pragma unroll
    for (int nt = 0; nt < 16; ++nt) {
#pragma unroll
        for (int i = 0; i < 4; ++i) {
            int row = m0 + quad * 4 + i;
            if (row < M) C[(size_t)row * HIDDEN + nt * 16 + r] = __float2bfloat16(acc[nt][i]);
        }
    }
}

// ---------------- fused aggregation + self-loop + bias + leaky-relu ----------------
// one wave per node; bf16 rows; padded CSR (-1 sentinels); coef from dinv (wave-uniform broadcast)
__global__ __launch_bounds__(256) void k_agg(const __hip_bfloat16* __restrict__ h,
                                             const float* __restrict__ bias,
                                             const int* __restrict__ off, const int* __restrict__ csrc,
                                             const float* __restrict__ dinv,
                                             __hip_bfloat16* __restrict__ out) {
    int node = (blockIdx.x * 256 + threadIdx.x) >> 6;
    int lane = threadIdx.x & 63;
    if (node >= N_NODES) return;
    float di = dinv[node];
    float selfc = di * di;
    ushort4 hv = ((const ushort4*)(h + (size_t)node * HIDDEN))[lane];
    float4 bv = ((const float4*)bias)[lane];
    float4 acc = make_float4(bv.x + bf2f(hv.x) * selfc, bv.y + bf2f(hv.y) * selfc,
                             bv.z + bf2f(hv.z) * selfc, bv.w + bf2f(hv.w) * selfc);
    int e = off[node], e1 = off[node + 1];
    for (; e < e1; e += 4) {
        int4 ss = *(const int4*)(csrc + e);
        int s0 = ss.x >= 0 ? ss.x : 0, s1 = ss.y >= 0 ? ss.y : 0;
        int s2 = ss.z >= 0 ? ss.z : 0, s3 = ss.w >= 0 ? ss.w : 0;
        float c0 = ss.x >= 0 ? dinv[s0] * di : 0.f;
        float c1 = ss.y >= 0 ? dinv[s1] * di : 0.f;
        float c2 = ss.z >= 0 ? dinv[s2] * di : 0.f;
        float c3 = ss.w >= 0 ? dinv[s3] * di : 0.f;
        ushort4 v0 = ((const ushort4*)(h + (size_t)s0 * HIDDEN))[lane];
        ushort4 v1 = ((const ushort4*)(h + (size_t)s1 * HIDDEN))[lane];
        ushort4 v2 = ((const ushort4*)(h + (size_t)s2 * HIDDEN))[lane];
        ushort4 v3 = ((const ushort4*)(h + (size_t)s3 * HIDDEN))[lane];
        acc.x += c0 * bf2f(v0.x) + c1 * bf2f(v1.x) + c2 * bf2f(v2.x) + c3 * bf2f(v3.x);
        acc.y += c0 * bf2f(v0.y) + c1 * bf2f(v1.y) + c2 * bf2f(v2.y) + c3 * bf2f(v3.y);
        acc.z += c0 * bf2f(v0.z) + c1 * bf2f(v1.z) + c2 * bf2f(v2.z) + c3 * bf2f(v3.z);
        acc.w += c0 * bf2f(v0.w) + c1 * bf2f(v1.w) + c2 * bf2f(v2.w) + c3 * bf2f(v3.w);
    }
    acc.x = acc.x >= 0.f ? acc.x : NEG_SLOPE * acc.x;
    acc.y = acc.y >= 0.f ? acc.y : NEG_SLOPE * acc.y;
    acc.z = acc.z >= 0.f ? acc.z : NEG_SLOPE * acc.z;
    acc.w = acc.w >= 0.f ? acc.w : NEG_SLOPE * acc.w;
    __hip_bfloat16 pk[4] = {__float2bfloat16(acc.x), __float2bfloat16(acc.y),
                            __float2bfloat16(acc.z), __float2bfloat16(acc.w)};
    *(uint2*)(out + (size_t)node * HIDDEN + lane * 4) = *(uint2*)pk;
}

// ---------------- global mean pool (partial sums + atomics), bf16 input ----------------
__global__ void k_pool(const __hip_bfloat16* __restrict__ h, const int* __restrict__ gstart,
                       const int* __restrict__ gcnt, float* __restrict__ pooled) {
    int g = blockIdx.x, chunk = blockIdx.y, t = threadIdx.x;
    int s = gstart[g], c = gcnt[g];
    int i0 = s + (int)(((long long)c * chunk) / 16);
    int i1 = s + (int)(((long long)c * (chunk + 1)) / 16);
    const unsigned short* hu = (const unsigned short*)h;
    float acc = 0.f;
    for (int i = i0; i < i1; ++i) acc += bf2f(hu[(size_t)i * HIDDEN + t]);
    atomicAdd(&pooled[g * HIDDEN + t], acc);
}

// ---------------- classifier head + softmax (one wave per graph) ----------------
__global__ void k_head(const float* __restrict__ pooled, const int* __restrict__ gcnt,
                       const float* __restrict__ Wc, const float* __restrict__ bc,
                       float* __restrict__ out) {
    int g = blockIdx.x; int l = threadIdx.x;  // 64 threads
    float inv = 1.0f / fmaxf((float)gcnt[g], 1.0f);
    float p[4];
#pragma unroll
    for (int i = 0; i < 4; i++) p[i] = pooled[g * HIDDEN + l + i * 64] * inv;
    __shared__ float logits[N_CLASSES];
#pragma unroll
    for (int j = 0; j < N_CLASSES; j++) {
        float s = 0.f;
#pragma unroll
        for (int i = 0; i < 4; i++) s += p[i] * Wc[(l + i * 64) * N_CLASSES + j];
        for (int o = 32; o > 0; o >>= 1) s += __shfl_down(s, o, 64);
        if (l == 0) logits[j] = s + bc[j];
    }
    __syncthreads();
    if (l == 0) {
        float m = logits[0];
        for (int j = 1; j < N_CLASSES; j++) m = fmaxf(m, logits[j]);
        float e[N_CLASSES]; float sum = 0.f;
        for (int j = 0; j < N_CLASSES; j++) { e[j] = expf(logits[j] - m); sum += e[j]; }
        for (int j = 0; j < N_CLASSES; j++) out[g * N_CLASSES + j] = e[j] / sum;
    }
}

extern "C" void kernel_launch(void* const* d_in, const int* in_sizes, int n_in,
                              void* d_out, int out_size, void* d_ws, size_t ws_size,
                              hipStream_t stream) {
    const float* x     = (const float*)d_in[0];
    const int*   edge  = (const int*)d_in[1];
    const int*   batch = (const int*)d_in[2];
    const float* W1 = (const float*)d_in[3];
    const float* b1 = (const float*)d_in[4];
    const float* W2 = (const float*)d_in[5];
    const float* b2 = (const float*)d_in[6];
    const float* W3 = (const float*)d_in[7];
    const float* b3 = (const float*)d_in[8];
    const float* Wc = (const float*)d_in[9];
    const float* bc = (const float*)d_in[10];
    float* out = (float*)d_out;
    const int* srcp = edge;
    const int* dstp = edge + N_EDGES;

    const int E_PAD = N_EDGES + 4 * N_NODES;  // capacity incl. padding

    char* ws = (char*)d_ws;
    size_t off = 0;
    auto alloc = [&](size_t bytes) -> char* {
        char* p = ws + off;
        off += (bytes + 255) & ~(size_t)255;
        return p;
    };
    __hip_bfloat16* hA  = (__hip_bfloat16*)alloc((size_t)N_NODES * HIDDEN * 2);
    __hip_bfloat16* hB  = (__hip_bfloat16*)alloc((size_t)N_NODES * HIDDEN * 2);
    __hip_bfloat16* Wt2 = (__hip_bfloat16*)alloc((size_t)HIDDEN * HIDDEN * 2);
    __hip_bfloat16* Wt3 = (__hip_bfloat16*)alloc((size_t)HIDDEN * HIDDEN * 2);
    int*   deg_cnt  = (int*)alloc((size_t)N_NODES * 4);
    float* dinv     = (float*)alloc((size_t)N_NODES * 4);
    int*   csr_off  = (int*)alloc((size_t)(N_NODES + 1) * 4);
    int*   cursor   = (int*)alloc((size_t)N_NODES * 4);
    int*   csr_src  = (int*)alloc((size_t)E_PAD * 4);
    float4* ax      = (float4*)alloc((size_t)N_NODES * 16);
    int*   gcnt     = (int*)alloc((size_t)N_GRAPHS * 4);
    int*   gstart   = (int*)alloc((size_t)N_GRAPHS * 4);
    float* pooled   = (float*)alloc((size_t)N_GRAPHS * HIDDEN * 4);
    int*   bsum     = (int*)alloc(128 * 4);

    hipMemsetAsync(deg_cnt, 0, (size_t)N_NODES * 4, stream);
    hipMemsetAsync(pooled, 0, (size_t)N_GRAPHS * HIDDEN * 4, stream);

    int eb4 = (N_EDGES / 4 + 255) / 256;   // 4 edges/thread
    int nb  = (N_NODES + 255) / 256;
    int sblocks = (N_NODES + 1023) / 1024;  // 98

    k_deg_hist<<<eb4, 256, 0, stream>>>(dstp, deg_cnt);
    k_graph_bounds<<<1, 64, 0, stream>>>(batch, gstart, gcnt);
    k_dinv<<<nb, 256, 0, stream>>>(deg_cnt, dinv);
    k_scanA<<<sblocks, 256, 0, stream>>>(deg_cnt, csr_off, bsum);
    k_scanB<<<1, 128, 0, stream>>>(bsum, sblocks);
    k_scanC<<<nb, 256, 0, stream>>>(csr_off, bsum, cursor, deg_cnt, csr_src);
    k_fill<<<eb4, 256, 0, stream>>>(srcp, dstp, cursor, csr_src);
    k_wprep<<<HIDDEN, HIDDEN, 0, stream>>>(W2, Wt2);
    k_wprep<<<HIDDEN, HIDDEN, 0, stream>>>(W3, Wt3);

    // layer 1 (reassociated): ax = Norm*x; h1 = leaky(ax @ W1 + b1)
    k_agg3<<<nb, 256, 0, stream>>>(x, csr_off, csr_src, dinv, ax);
    k_l1<<<N_NODES, 256, 0, stream>>>(ax, W1, b1, hA);

    int aggb  = (N_NODES + 3) / 4;
    int gemmb = (N_NODES + 63) / 64;
    // layer 2
    k_gemm_mfma<<<gemmb, 256, 0, stream>>>(hA, Wt2, hB, N_NODES);
    k_agg<<<aggb, 256, 0, stream>>>(hB, b2, csr_off, csr_src, dinv, hA);
    // layer 3
    k_gemm_mfma<<<gemmb, 256, 0, stream>>>(hA, Wt3, hB, N_NODES);
    k_agg<<<aggb, 256, 0, stream>>>(hB, b3, csr_off, csr_src, dinv, hA);
    // pool + head
    dim3 pg(N_GRAPHS, 16);
    k_pool<<<pg, 256, 0, stream>>>(hA, gstart, gcnt, pooled);
    k_head<<<N_GRAPHS, 64, 0, stream>>>(pooled, gcnt, Wc, bc, out);
}

// Round 7
// 809.537 us; speedup vs baseline: 1.0689x; 1.0689x over previous
//
#include <hip/hip_runtime.h>
#include <hip/hip_bf16.h>
#include <cstdint>
#include <cstddef>

#define N_NODES   100000
#define N_EDGES   1600000
#define N_GRAPHS  64
#define HIDDEN    256
#define N_CLASSES 10
#define NEG_SLOPE 0.01f

typedef __attribute__((ext_vector_type(8))) short bfrag8;   // 8 bf16 (4 VGPRs)
typedef __attribute__((ext_vector_type(4))) float f32x4;    // MFMA C/D

__device__ __forceinline__ float bf2f(unsigned short u) {
    return __uint_as_float(((unsigned int)u) << 16);
}

// ---------------- degree histogram (4 edges/thread, 4 atomics in flight) ----------------
__global__ void k_deg_hist(const int* __restrict__ dst, int* __restrict__ cnt) {
    int e = (blockIdx.x * 256 + threadIdx.x) * 4;
    if (e >= N_EDGES) return;
    int4 d4 = *(const int4*)(dst + e);
    atomicAdd(&cnt[d4.x], 1);
    atomicAdd(&cnt[d4.y], 1);
    atomicAdd(&cnt[d4.z], 1);
    atomicAdd(&cnt[d4.w], 1);
}

// ---------------- graph boundaries via binary search (batch is sorted) ----------------
__global__ void k_graph_bounds(const int* __restrict__ batch,
                               int* __restrict__ gstart, int* __restrict__ gcnt) {
    int g = threadIdx.x;  // 0..63
    int lo = 0, hi = N_NODES;
    while (lo < hi) { int mid = (lo + hi) >> 1; if (batch[mid] < g) lo = mid + 1; else hi = mid; }
    __shared__ int sh[N_GRAPHS + 1];
    sh[g] = lo;
    if (g == 0) sh[N_GRAPHS] = N_NODES;
    __syncthreads();
    gstart[g] = sh[g];
    gcnt[g]   = sh[g + 1] - sh[g];
}

__global__ void k_dinv(const int* __restrict__ cnt, float* __restrict__ dinv) {
    int i = blockIdx.x * 256 + threadIdx.x;
    if (i < N_NODES) dinv[i] = rsqrtf((float)cnt[i] + 1.0f);
}

// ---------------- exclusive scan of PADDED degree counts (CSR offsets) ----------------
// degrees rounded up to multiple of 4 so the agg loop is exact 4-wide
__global__ void k_scanA(const int* __restrict__ cnt, int* __restrict__ out, int* __restrict__ bsum) {
    __shared__ int sh[256];
    int tid = threadIdx.x;
    int base = blockIdx.x * 1024 + tid * 4;
    int v[4]; int s = 0;
#pragma unroll
    for (int i = 0; i < 4; i++) {
        int idx = base + i;
        v[i] = (idx < N_NODES) ? ((cnt[idx] + 3) & ~3) : 0;
        s += v[i];
    }
    sh[tid] = s; __syncthreads();
    for (int off = 1; off < 256; off <<= 1) {
        int t = (tid >= off) ? sh[tid - off] : 0;
        __syncthreads();
        sh[tid] += t;
        __syncthreads();
    }
    int excl = sh[tid] - s;
    if (tid == 255) bsum[blockIdx.x] = sh[255];
#pragma unroll
    for (int i = 0; i < 4; i++) { int idx = base + i; if (idx < N_NODES) out[idx] = excl; excl += v[i]; }
}

__global__ void k_scanB(int* __restrict__ bsum, int nb) {
    __shared__ int sh[128];
    int tid = threadIdx.x;
    int v = (tid < nb) ? bsum[tid] : 0;
    sh[tid] = v; __syncthreads();
    for (int off = 1; off < 128; off <<= 1) {
        int t = (tid >= off) ? sh[tid - off] : 0;
        __syncthreads();
        sh[tid] += t;
        __syncthreads();
    }
    if (tid < nb) bsum[tid] = sh[tid] - v;  // exclusive
}

// finalize offsets + init cursor + zero-records into padding slots
__global__ void k_scanC(int* __restrict__ off_arr, const int* __restrict__ bsum,
                        int* __restrict__ cursor, const int* __restrict__ cnt,
                        int2* __restrict__ rec) {
    int i = blockIdx.x * 256 + threadIdx.x;
    if (i < N_NODES) {
        int v = off_arr[i] + bsum[i >> 10];
        off_arr[i] = v;
        cursor[i]  = v;
        int c  = cnt[i];
        int cp = (c + 3) & ~3;
        for (int p = v + c; p < v + cp; ++p) rec[p] = make_int2(0, 0);
        if (i == N_NODES - 1) off_arr[N_NODES] = v + cp;
    }
}

// ---------------- CSR fill: scatter one 8-byte record {src, coef} per edge ----------------
__global__ void k_fill(const int* __restrict__ src, const int* __restrict__ dst,
                       const float* __restrict__ dinv, int* __restrict__ cursor,
                       int2* __restrict__ rec) {
    int e = (blockIdx.x * 256 + threadIdx.x) * 4;
    if (e >= N_EDGES) return;
    int4 d4 = *(const int4*)(dst + e);
    int4 s4 = *(const int4*)(src + e);
    float c0 = dinv[s4.x] * dinv[d4.x];
    float c1 = dinv[s4.y] * dinv[d4.y];
    float c2 = dinv[s4.z] * dinv[d4.z];
    float c3 = dinv[s4.w] * dinv[d4.w];
    int p0 = atomicAdd(&cursor[d4.x], 1);
    int p1 = atomicAdd(&cursor[d4.y], 1);
    int p2 = atomicAdd(&cursor[d4.z], 1);
    int p3 = atomicAdd(&cursor[d4.w], 1);
    rec[p0] = make_int2(s4.x, __float_as_int(c0));
    rec[p1] = make_int2(s4.y, __float_as_int(c1));
    rec[p2] = make_int2(s4.z, __float_as_int(c2));
    rec[p3] = make_int2(s4.w, __float_as_int(c3));
}

// ---------------- weight prep: W[k][n] fp32 -> Wt[n][k] bf16 ----------------
__global__ void k_wprep(const float* __restrict__ W, __hip_bfloat16* __restrict__ Wt) {
    int n = blockIdx.x; int k = threadIdx.x;  // 256 x 256
    Wt[n * HIDDEN + k] = __float2bfloat16(W[k * HIDDEN + n]);
}

// ---------------- layer-1 reassociated: ax = Norm * x  (3 features, exact) ----------------
__global__ void k_agg3(const float* __restrict__ x, const int* __restrict__ off,
                       const int2* __restrict__ rec, const float* __restrict__ dinv,
                       float4* __restrict__ ax) {
    int i = blockIdx.x * 256 + threadIdx.x;
    if (i >= N_NODES) return;
    float di = dinv[i];
    float selfc = di * di;
    float a0 = x[i * 3 + 0] * selfc, a1 = x[i * 3 + 1] * selfc, a2 = x[i * 3 + 2] * selfc;
    int e = off[i], e1 = off[i + 1];
    for (; e < e1; e += 4) {
        const int4* rp = (const int4*)(rec + e);
        int4 r01 = rp[0];  // {s0, c0, s1, c1}
        int4 r23 = rp[1];  // {s2, c2, s3, c3}
        int s0 = r01.x, s1 = r01.z, s2 = r23.x, s3 = r23.z;
        float c0 = __int_as_float(r01.y), c1 = __int_as_float(r01.w);
        float c2 = __int_as_float(r23.y), c3 = __int_as_float(r23.w);
        a0 += c0 * x[s0 * 3 + 0] + c1 * x[s1 * 3 + 0] + c2 * x[s2 * 3 + 0] + c3 * x[s3 * 3 + 0];
        a1 += c0 * x[s0 * 3 + 1] + c1 * x[s1 * 3 + 1] + c2 * x[s2 * 3 + 1] + c3 * x[s3 * 3 + 1];
        a2 += c0 * x[s0 * 3 + 2] + c1 * x[s1 * 3 + 2] + c2 * x[s2 * 3 + 2] + c3 * x[s3 * 3 + 2];
    }
    ax[i] = make_float4(a0, a1, a2, 0.f);
}

// h1 = leaky(ax @ W1 + b1), bf16 out
__global__ void k_l1(const float4* __restrict__ ax, const float* __restrict__ W1,
                     const float* __restrict__ b1, __hip_bfloat16* __restrict__ out) {
    int node = blockIdx.x; int c = threadIdx.x;
    float4 a = ax[node];
    float v = a.x * W1[c] + a.y * W1[HIDDEN + c] + a.z * W1[2 * HIDDEN + c] + b1[c];
    v = v >= 0.f ? v : NEG_SLOPE * v;
    out[(size_t)node * HIDDEN + c] = __float2bfloat16(v);
}

// ---------------- MFMA GEMM with LDS-staged Wt ----------------
__global__ __launch_bounds__(256) void k_gemm_mfma(const __hip_bfloat16* __restrict__ A,
                                                   const __hip_bfloat16* __restrict__ Wt,
                                                   __hip_bfloat16* __restrict__ C, int M) {
    __shared__ short Bs[256 * 40];  // 20 KB
    int tid = threadIdx.x;
    int wv = tid >> 6, lane = tid & 63;
    int quad = lane >> 4, r = lane & 15;
    int m0 = blockIdx.x * 64 + wv * 16;
    int arow = m0 + r; if (arow >= M) arow = M - 1;
    const short* Ab = (const short*)A + (size_t)arow * HIDDEN + quad * 8;

    bfrag8 af[8];
#pragma unroll
    for (int c = 0; c < 8; ++c) af[c] = *(const bfrag8*)(Ab + c * 32);

    f32x4 acc[16];
#pragma unroll
    for (int i = 0; i < 16; i++) acc[i] = (f32x4){0.f, 0.f, 0.f, 0.f};

    const float4* wsrc = (const float4*)((const short*)Wt + (size_t)tid * HIDDEN);  // row n=tid
    float4 st[4];
#pragma unroll
    for (int i = 0; i < 4; ++i) st[i] = wsrc[i];  // chunk 0

#pragma unroll
    for (int c = 0; c < 8; ++c) {
        __syncthreads();
        float4* bdst = (float4*)(Bs + tid * 40);
#pragma unroll
        for (int i = 0; i < 4; ++i) bdst[i] = st[i];
        __syncthreads();
        if (c < 7) {
#pragma unroll
            for (int i = 0; i < 4; ++i) st[i] = wsrc[(c + 1) * 4 + i];
        }
#pragma unroll
        for (int nt = 0; nt < 16; ++nt) {
            bfrag8 b = *(const bfrag8*)(Bs + (nt * 16 + r) * 40 + quad * 8);
            acc[nt] = __builtin_amdgcn_mfma_f32_16x16x32_bf16(af[c], b, acc[nt], 0, 0, 0);
        }
    }
#pragma unroll
    for (int nt = 0; nt < 16; ++nt) {
#pragma unroll
        for (int i = 0; i < 4; ++i) {
            int row = m0 + quad * 4 + i;
            if (row < M) C[(size_t)row * HIDDEN + nt * 16 + r] = __float2bfloat16(acc[nt][i]);
        }
    }
}

// ---------------- fused aggregation + self-loop + bias + leaky-relu ----------------
// one wave per node; bf16 rows; padded CSR of {src,coef} records -> branch-free 4-wide loop
__global__ __launch_bounds__(256) void k_agg(const __hip_bfloat16* __restrict__ h,
                                             const float* __restrict__ bias,
                                             const int* __restrict__ off, const int2* __restrict__ rec,
                                             const float* __restrict__ dinv,
                                             __hip_bfloat16* __restrict__ out) {
    int node = (blockIdx.x * 256 + threadIdx.x) >> 6;
    int lane = threadIdx.x & 63;
    if (node >= N_NODES) return;
    float di = dinv[node];
    float selfc = di * di;
    ushort4 hv = ((const ushort4*)(h + (size_t)node * HIDDEN))[lane];
    float4 bv = ((const float4*)bias)[lane];
    float4 acc = make_float4(bv.x + bf2f(hv.x) * selfc, bv.y + bf2f(hv.y) * selfc,
                             bv.z + bf2f(hv.z) * selfc, bv.w + bf2f(hv.w) * selfc);
    int e = off[node], e1 = off[node + 1];
    for (; e < e1; e += 4) {
        const int4* rp = (const int4*)(rec + e);
        int4 r01 = rp[0];  // {s0, c0, s1, c1}
        int4 r23 = rp[1];  // {s2, c2, s3, c3}
        float c0 = __int_as_float(r01.y), c1 = __int_as_float(r01.w);
        float c2 = __int_as_float(r23.y), c3 = __int_as_float(r23.w);
        ushort4 v0 = ((const ushort4*)(h + (size_t)r01.x * HIDDEN))[lane];
        ushort4 v1 = ((const ushort4*)(h + (size_t)r01.z * HIDDEN))[lane];
        ushort4 v2 = ((const ushort4*)(h + (size_t)r23.x * HIDDEN))[lane];
        ushort4 v3 = ((const ushort4*)(h + (size_t)r23.z * HIDDEN))[lane];
        acc.x += c0 * bf2f(v0.x) + c1 * bf2f(v1.x) + c2 * bf2f(v2.x) + c3 * bf2f(v3.x);
        acc.y += c0 * bf2f(v0.y) + c1 * bf2f(v1.y) + c2 * bf2f(v2.y) + c3 * bf2f(v3.y);
        acc.z += c0 * bf2f(v0.z) + c1 * bf2f(v1.z) + c2 * bf2f(v2.z) + c3 * bf2f(v3.z);
        acc.w += c0 * bf2f(v0.w) + c1 * bf2f(v1.w) + c2 * bf2f(v2.w) + c3 * bf2f(v3.w);
    }
    acc.x = acc.x >= 0.f ? acc.x : NEG_SLOPE * acc.x;
    acc.y = acc.y >= 0.f ? acc.y : NEG_SLOPE * acc.y;
    acc.z = acc.z >= 0.f ? acc.z : NEG_SLOPE * acc.z;
    acc.w = acc.w >= 0.f ? acc.w : NEG_SLOPE * acc.w;
    __hip_bfloat16 pk[4] = {__float2bfloat16(acc.x), __float2bfloat16(acc.y),
                            __float2bfloat16(acc.z), __float2bfloat16(acc.w)};
    *(uint2*)(out + (size_t)node * HIDDEN + lane * 4) = *(uint2*)pk;
}

// ---------------- global mean pool (partial sums + atomics), bf16 input ----------------
__global__ void k_pool(const __hip_bfloat16* __restrict__ h, const int* __restrict__ gstart,
                       const int* __restrict__ gcnt, float* __restrict__ pooled) {
    int g = blockIdx.x, chunk = blockIdx.y, t = threadIdx.x;
    int s = gstart[g], c = gcnt[g];
    int i0 = s + (int)(((long long)c * chunk) / 16);
    int i1 = s + (int)(((long long)c * (chunk + 1)) / 16);
    const unsigned short* hu = (const unsigned short*)h;
    float acc = 0.f;
    for (int i = i0; i < i1; ++i) acc += bf2f(hu[(size_t)i * HIDDEN + t]);
    atomicAdd(&pooled[g * HIDDEN + t], acc);
}

// ---------------- classifier head + softmax (one wave per graph) ----------------
__global__ void k_head(const float* __restrict__ pooled, const int* __restrict__ gcnt,
                       const float* __restrict__ Wc, const float* __restrict__ bc,
                       float* __restrict__ out) {
    int g = blockIdx.x; int l = threadIdx.x;  // 64 threads
    float inv = 1.0f / fmaxf((float)gcnt[g], 1.0f);
    float p[4];
#pragma unroll
    for (int i = 0; i < 4; i++) p[i] = pooled[g * HIDDEN + l + i * 64] * inv;
    __shared__ float logits[N_CLASSES];
#pragma unroll
    for (int j = 0; j < N_CLASSES; j++) {
        float s = 0.f;
#pragma unroll
        for (int i = 0; i < 4; i++) s += p[i] * Wc[(l + i * 64) * N_CLASSES + j];
        for (int o = 32; o > 0; o >>= 1) s += __shfl_down(s, o, 64);
        if (l == 0) logits[j] = s + bc[j];
    }
    __syncthreads();
    if (l == 0) {
        float m = logits[0];
        for (int j = 1; j < N_CLASSES; j++) m = fmaxf(m, logits[j]);
        float e[N_CLASSES]; float sum = 0.f;
        for (int j = 0; j < N_CLASSES; j++) { e[j] = expf(logits[j] - m); sum += e[j]; }
        for (int j = 0; j < N_CLASSES; j++) out[g * N_CLASSES + j] = e[j] / sum;
    }
}

extern "C" void kernel_launch(void* const* d_in, const int* in_sizes, int n_in,
                              void* d_out, int out_size, void* d_ws, size_t ws_size,
                              hipStream_t stream) {
    const float* x     = (const float*)d_in[0];
    const int*   edge  = (const int*)d_in[1];
    const int*   batch = (const int*)d_in[2];
    const float* W1 = (const float*)d_in[3];
    const float* b1 = (const float*)d_in[4];
    const float* W2 = (const float*)d_in[5];
    const float* b2 = (const float*)d_in[6];
    const float* W3 = (const float*)d_in[7];
    const float* b3 = (const float*)d_in[8];
    const float* Wc = (const float*)d_in[9];
    const float* bc = (const float*)d_in[10];
    float* out = (float*)d_out;
    const int* srcp = edge;
    const int* dstp = edge + N_EDGES;

    const int E_PAD = N_EDGES + 4 * N_NODES;  // capacity incl. padding

    char* ws = (char*)d_ws;
    size_t off = 0;
    auto alloc = [&](size_t bytes) -> char* {
        char* p = ws + off;
        off += (bytes + 255) & ~(size_t)255;
        return p;
    };
    __hip_bfloat16* hA  = (__hip_bfloat16*)alloc((size_t)N_NODES * HIDDEN * 2);
    __hip_bfloat16* hB  = (__hip_bfloat16*)alloc((size_t)N_NODES * HIDDEN * 2);
    __hip_bfloat16* Wt2 = (__hip_bfloat16*)alloc((size_t)HIDDEN * HIDDEN * 2);
    __hip_bfloat16* Wt3 = (__hip_bfloat16*)alloc((size_t)HIDDEN * HIDDEN * 2);
    int*   deg_cnt  = (int*)alloc((size_t)N_NODES * 4);
    float* dinv     = (float*)alloc((size_t)N_NODES * 4);
    int*   csr_off  = (int*)alloc((size_t)(N_NODES + 1) * 4);
    int*   cursor   = (int*)alloc((size_t)N_NODES * 4);
    int2*  csr_rec  = (int2*)alloc((size_t)E_PAD * 8);
    float4* ax      = (float4*)alloc((size_t)N_NODES * 16);
    int*   gcnt     = (int*)alloc((size_t)N_GRAPHS * 4);
    int*   gstart   = (int*)alloc((size_t)N_GRAPHS * 4);
    float* pooled   = (float*)alloc((size_t)N_GRAPHS * HIDDEN * 4);
    int*   bsum     = (int*)alloc(128 * 4);

    hipMemsetAsync(deg_cnt, 0, (size_t)N_NODES * 4, stream);
    hipMemsetAsync(pooled, 0, (size_t)N_GRAPHS * HIDDEN * 4, stream);

    int eb4 = (N_EDGES / 4 + 255) / 256;   // 4 edges/thread
    int nb  = (N_NODES + 255) / 256;
    int sblocks = (N_NODES + 1023) / 1024;  // 98

    k_deg_hist<<<eb4, 256, 0, stream>>>(dstp, deg_cnt);
    k_graph_bounds<<<1, 64, 0, stream>>>(batch, gstart, gcnt);
    k_dinv<<<nb, 256, 0, stream>>>(deg_cnt, dinv);
    k_scanA<<<sblocks, 256, 0, stream>>>(deg_cnt, csr_off, bsum);
    k_scanB<<<1, 128, 0, stream>>>(bsum, sblocks);
    k_scanC<<<nb, 256, 0, stream>>>(csr_off, bsum, cursor, deg_cnt, csr_rec);
    k_fill<<<eb4, 256, 0, stream>>>(srcp, dstp, dinv, cursor, csr_rec);
    k_wprep<<<HIDDEN, HIDDEN, 0, stream>>>(W2, Wt2);
    k_wprep<<<HIDDEN, HIDDEN, 0, stream>>>(W3, Wt3);

    // layer 1 (reassociated): ax = Norm*x; h1 = leaky(ax @ W1 + b1)
    k_agg3<<<nb, 256, 0, stream>>>(x, csr_off, csr_rec, dinv, ax);
    k_l1<<<N_NODES, 256, 0, stream>>>(ax, W1, b1, hA);

    int aggb  = (N_NODES + 3) / 4;
    int gemmb = (N_NODES + 63) / 64;
    // layer 2
    k_gemm_mfma<<<gemmb, 256, 0, stream>>>(hA, Wt2, hB, N_NODES);
    k_agg<<<aggb, 256, 0, stream>>>(hB, b2, csr_off, csr_rec, dinv, hA);
    // layer 3
    k_gemm_mfma<<<gemmb, 256, 0, stream>>>(hA, Wt3, hB, N_NODES);
    k_agg<<<aggb, 256, 0, stream>>>(hB, b3, csr_off, csr_rec, dinv, hA);
    // pool + head
    dim3 pg(N_GRAPHS, 16);
    k_pool<<<pg, 256, 0, stream>>>(hA, gstart, gcnt, pooled);
    k_head<<<N_GRAPHS, 64, 0, stream>>>(pooled, gcnt, Wc, bc, out);
}

// Round 8
// 798.503 us; speedup vs baseline: 1.0837x; 1.0138x over previous
//
#include <hip/hip_runtime.h>
#include <hip/hip_bf16.h>
#include <cstdint>
#include <cstddef>

#define N_NODES   100000
#define N_EDGES   1600000
#define N_GRAPHS  64
#define HIDDEN    256
#define N_CLASSES 10
#define NEG_SLOPE 0.01f

#define E_PAD (N_EDGES + 4 * N_NODES)

typedef __attribute__((ext_vector_type(8))) short bfrag8;   // 8 bf16 (4 VGPRs)
typedef __attribute__((ext_vector_type(4))) float f32x4;    // MFMA C/D

__device__ __forceinline__ float bf2f(unsigned short u) {
    return __uint_as_float(((unsigned int)u) << 16);
}

// ---------------- degree histogram (4 edges/thread, 4 atomics in flight) ----------------
__global__ void k_deg_hist(const int* __restrict__ dst, int* __restrict__ cnt) {
    int e = (blockIdx.x * 256 + threadIdx.x) * 4;
    if (e >= N_EDGES) return;
    int4 d4 = *(const int4*)(dst + e);
    atomicAdd(&cnt[d4.x], 1);
    atomicAdd(&cnt[d4.y], 1);
    atomicAdd(&cnt[d4.z], 1);
    atomicAdd(&cnt[d4.w], 1);
}

// ---------------- graph boundaries via binary search (batch is sorted) ----------------
__global__ void k_graph_bounds(const int* __restrict__ batch,
                               int* __restrict__ gstart, int* __restrict__ gcnt) {
    int g = threadIdx.x;  // 0..63
    int lo = 0, hi = N_NODES;
    while (lo < hi) { int mid = (lo + hi) >> 1; if (batch[mid] < g) lo = mid + 1; else hi = mid; }
    __shared__ int sh[N_GRAPHS + 1];
    sh[g] = lo;
    if (g == 0) sh[N_GRAPHS] = N_NODES;
    __syncthreads();
    gstart[g] = sh[g];
    gcnt[g]   = sh[g + 1] - sh[g];
}

__global__ void k_dinv(const int* __restrict__ cnt, float* __restrict__ dinv) {
    int i = blockIdx.x * 256 + threadIdx.x;
    if (i < N_NODES) dinv[i] = rsqrtf((float)cnt[i] + 1.0f);
}

// ---------------- exclusive scan of PADDED degree counts (CSR offsets) ----------------
// degrees rounded up to multiple of 4 so the agg loop is exact 4-wide
__global__ void k_scanA(const int* __restrict__ cnt, int* __restrict__ out, int* __restrict__ bsum) {
    __shared__ int sh[256];
    int tid = threadIdx.x;
    int base = blockIdx.x * 1024 + tid * 4;
    int v[4]; int s = 0;
#pragma unroll
    for (int i = 0; i < 4; i++) {
        int idx = base + i;
        v[i] = (idx < N_NODES) ? ((cnt[idx] + 3) & ~3) : 0;
        s += v[i];
    }
    sh[tid] = s; __syncthreads();
    for (int off = 1; off < 256; off <<= 1) {
        int t = (tid >= off) ? sh[tid - off] : 0;
        __syncthreads();
        sh[tid] += t;
        __syncthreads();
    }
    int excl = sh[tid] - s;
    if (tid == 255) bsum[blockIdx.x] = sh[255];
#pragma unroll
    for (int i = 0; i < 4; i++) { int idx = base + i; if (idx < N_NODES) out[idx] = excl; excl += v[i]; }
}

__global__ void k_scanB(int* __restrict__ bsum, int nb) {
    __shared__ int sh[128];
    int tid = threadIdx.x;
    int v = (tid < nb) ? bsum[tid] : 0;
    sh[tid] = v; __syncthreads();
    for (int off = 1; off < 128; off <<= 1) {
        int t = (tid >= off) ? sh[tid - off] : 0;
        __syncthreads();
        sh[tid] += t;
        __syncthreads();
    }
    if (tid < nb) bsum[tid] = sh[tid] - v;  // exclusive
}

// finalize offsets + init cursor + sentinel records into padding slots
__global__ void k_scanC(int* __restrict__ off_arr, const int* __restrict__ bsum,
                        int* __restrict__ cursor, const int* __restrict__ cnt,
                        int2* __restrict__ rec) {
    int i = blockIdx.x * 256 + threadIdx.x;
    if (i < N_NODES) {
        int v = off_arr[i] + bsum[i >> 10];
        off_arr[i] = v;
        cursor[i]  = v;
        int c  = cnt[i];
        int cp = (c + 3) & ~3;
        for (int p = v + c; p < v + cp; ++p) rec[p] = make_int2(-1, 0);
        if (i == N_NODES - 1) off_arr[N_NODES] = v + cp;
    }
}

// ---------------- CSR fill: scatter one 8-byte record {src, dst} per edge (NO gathers) ----------------
__global__ void k_fill(const int* __restrict__ src, const int* __restrict__ dst,
                       int* __restrict__ cursor, int2* __restrict__ rec) {
    int e = (blockIdx.x * 256 + threadIdx.x) * 4;
    if (e >= N_EDGES) return;
    int4 d4 = *(const int4*)(dst + e);
    int4 s4 = *(const int4*)(src + e);
    int p0 = atomicAdd(&cursor[d4.x], 1);
    int p1 = atomicAdd(&cursor[d4.y], 1);
    int p2 = atomicAdd(&cursor[d4.z], 1);
    int p3 = atomicAdd(&cursor[d4.w], 1);
    rec[p0] = make_int2(s4.x, d4.x);
    rec[p1] = make_int2(s4.y, d4.y);
    rec[p2] = make_int2(s4.z, d4.z);
    rec[p3] = make_int2(s4.w, d4.w);
}

// ---------------- coef pass: rewrite records {src,dst} -> {src,coef} (fully linear) ----------------
__global__ void k_coef(int2* __restrict__ rec, const float* __restrict__ dinv,
                       const int* __restrict__ off_end) {
    int p = blockIdx.x * 256 + threadIdx.x;
    if (p >= off_end[0]) return;
    int2 r = rec[p];
    if (r.x < 0) {
        rec[p] = make_int2(0, 0);  // padding: src=0, coef=0
    } else {
        float c = dinv[r.x] * dinv[r.y];
        rec[p] = make_int2(r.x, __float_as_int(c));
    }
}

// ---------------- weight prep: W[k][n] fp32 -> Wt[n][k] bf16 ----------------
__global__ void k_wprep(const float* __restrict__ W, __hip_bfloat16* __restrict__ Wt) {
    int n = blockIdx.x; int k = threadIdx.x;  // 256 x 256
    Wt[n * HIDDEN + k] = __float2bfloat16(W[k * HIDDEN + n]);
}

// ---------------- layer-1 reassociated: ax = Norm * x  (3 features, exact) ----------------
__global__ void k_agg3(const float* __restrict__ x, const int* __restrict__ off,
                       const int2* __restrict__ rec, const float* __restrict__ dinv,
                       float4* __restrict__ ax) {
    int i = blockIdx.x * 256 + threadIdx.x;
    if (i >= N_NODES) return;
    float di = dinv[i];
    float selfc = di * di;
    float a0 = x[i * 3 + 0] * selfc, a1 = x[i * 3 + 1] * selfc, a2 = x[i * 3 + 2] * selfc;
    int e = off[i], e1 = off[i + 1];
    for (; e < e1; e += 4) {
        const int4* rp = (const int4*)(rec + e);
        int4 r01 = rp[0];  // {s0, c0, s1, c1}
        int4 r23 = rp[1];  // {s2, c2, s3, c3}
        int s0 = r01.x, s1 = r01.z, s2 = r23.x, s3 = r23.z;
        float c0 = __int_as_float(r01.y), c1 = __int_as_float(r01.w);
        float c2 = __int_as_float(r23.y), c3 = __int_as_float(r23.w);
        a0 += c0 * x[s0 * 3 + 0] + c1 * x[s1 * 3 + 0] + c2 * x[s2 * 3 + 0] + c3 * x[s3 * 3 + 0];
        a1 += c0 * x[s0 * 3 + 1] + c1 * x[s1 * 3 + 1] + c2 * x[s2 * 3 + 1] + c3 * x[s3 * 3 + 1];
        a2 += c0 * x[s0 * 3 + 2] + c1 * x[s1 * 3 + 2] + c2 * x[s2 * 3 + 2] + c3 * x[s3 * 3 + 2];
    }
    ax[i] = make_float4(a0, a1, a2, 0.f);
}

// h1 = leaky(ax @ W1 + b1), bf16 out
__global__ void k_l1(const float4* __restrict__ ax, const float* __restrict__ W1,
                     const float* __restrict__ b1, __hip_bfloat16* __restrict__ out) {
    int node = blockIdx.x; int c = threadIdx.x;
    float4 a = ax[node];
    float v = a.x * W1[c] + a.y * W1[HIDDEN + c] + a.z * W1[2 * HIDDEN + c] + b1[c];
    v = v >= 0.f ? v : NEG_SLOPE * v;
    out[(size_t)node * HIDDEN + c] = __float2bfloat16(v);
}

// ---------------- MFMA GEMM with LDS-staged Wt ----------------
__global__ __launch_bounds__(256) void k_gemm_mfma(const __hip_bfloat16* __restrict__ A,
                                                   const __hip_bfloat16* __restrict__ Wt,
                                                   __hip_bfloat16* __restrict__ C, int M) {
    __shared__ short Bs[256 * 40];  // 20 KB
    int tid = threadIdx.x;
    int wv = tid >> 6, lane = tid & 63;
    int quad = lane >> 4, r = lane & 15;
    int m0 = blockIdx.x * 64 + wv * 16;
    int arow = m0 + r; if (arow >= M) arow = M - 1;
    const short* Ab = (const short*)A + (size_t)arow * HIDDEN + quad * 8;

    bfrag8 af[8];
#pragma unroll
    for (int c = 0; c < 8; ++c) af[c] = *(const bfrag8*)(Ab + c * 32);

    f32x4 acc[16];
#pragma unroll
    for (int i = 0; i < 16; i++) acc[i] = (f32x4){0.f, 0.f, 0.f, 0.f};

    const float4* wsrc = (const float4*)((const short*)Wt + (size_t)tid * HIDDEN);  // row n=tid
    float4 st[4];
#pragma unroll
    for (int i = 0; i < 4; ++i) st[i] = wsrc[i];  // chunk 0

#pragma unroll
    for (int c = 0; c < 8; ++c) {
        __syncthreads();
        float4* bdst = (float4*)(Bs + tid * 40);
#pragma unroll
        for (int i = 0; i < 4; ++i) bdst[i] = st[i];
        __syncthreads();
        if (c < 7) {
#pragma unroll
            for (int i = 0; i < 4; ++i) st[i] = wsrc[(c + 1) * 4 + i];
        }
#pragma unroll
        for (int nt = 0; nt < 16; ++nt) {
            bfrag8 b = *(const bfrag8*)(Bs + (nt * 16 + r) * 40 + quad * 8);
            acc[nt] = __builtin_amdgcn_mfma_f32_16x16x32_bf16(af[c], b, acc[nt], 0, 0, 0);
        }
    }
#pragma unroll
    for (int nt = 0; nt < 16; ++nt) {
#pragma unroll
        for (int i = 0; i < 4; ++i) {
            int row = m0 + quad * 4 + i;
            if (row < M) C[(size_t)row * HIDDEN + nt * 16 + r] = __float2bfloat16(acc[nt][i]);
        }
    }
}

// ---------------- fused aggregation + self-loop + bias + leaky-relu ----------------
// one wave per node; bf16 rows; padded CSR of {src,coef} records -> branch-free 4-wide loop
__global__ __launch_bounds__(256) void k_agg(const __hip_bfloat16* __restrict__ h,
                                             const float* __restrict__ bias,
                                             const int* __restrict__ off, const int2* __restrict__ rec,
                                             const float* __restrict__ dinv,
                                             __hip_bfloat16* __restrict__ out) {
    int node = (blockIdx.x * 256 + threadIdx.x) >> 6;
    int lane = threadIdx.x & 63;
    if (node >= N_NODES) return;
    float di = dinv[node];
    float selfc = di * di;
    ushort4 hv = ((const ushort4*)(h + (size_t)node * HIDDEN))[lane];
    float4 bv = ((const float4*)bias)[lane];
    float4 acc = make_float4(bv.x + bf2f(hv.x) * selfc, bv.y + bf2f(hv.y) * selfc,
                             bv.z + bf2f(hv.z) * selfc, bv.w + bf2f(hv.w) * selfc);
    int e = off[node], e1 = off[node + 1];
    for (; e < e1; e += 4) {
        const int4* rp = (const int4*)(rec + e);
        int4 r01 = rp[0];  // {s0, c0, s1, c1}
        int4 r23 = rp[1];  // {s2, c2, s3, c3}
        float c0 = __int_as_float(r01.y), c1 = __int_as_float(r01.w);
        float c2 = __int_as_float(r23.y), c3 = __int_as_float(r23.w);
        ushort4 v0 = ((const ushort4*)(h + (size_t)r01.x * HIDDEN))[lane];
        ushort4 v1 = ((const ushort4*)(h + (size_t)r01.z * HIDDEN))[lane];
        ushort4 v2 = ((const ushort4*)(h + (size_t)r23.x * HIDDEN))[lane];
        ushort4 v3 = ((const ushort4*)(h + (size_t)r23.z * HIDDEN))[lane];
        acc.x += c0 * bf2f(v0.x) + c1 * bf2f(v1.x) + c2 * bf2f(v2.x) + c3 * bf2f(v3.x);
        acc.y += c0 * bf2f(v0.y) + c1 * bf2f(v1.y) + c2 * bf2f(v2.y) + c3 * bf2f(v3.y);
        acc.z += c0 * bf2f(v0.z) + c1 * bf2f(v1.z) + c2 * bf2f(v2.z) + c3 * bf2f(v3.z);
        acc.w += c0 * bf2f(v0.w) + c1 * bf2f(v1.w) + c2 * bf2f(v2.w) + c3 * bf2f(v3.w);
    }
    acc.x = acc.x >= 0.f ? acc.x : NEG_SLOPE * acc.x;
    acc.y = acc.y >= 0.f ? acc.y : NEG_SLOPE * acc.y;
    acc.z = acc.z >= 0.f ? acc.z : NEG_SLOPE * acc.z;
    acc.w = acc.w >= 0.f ? acc.w : NEG_SLOPE * acc.w;
    __hip_bfloat16 pk[4] = {__float2bfloat16(acc.x), __float2bfloat16(acc.y),
                            __float2bfloat16(acc.z), __float2bfloat16(acc.w)};
    *(uint2*)(out + (size_t)node * HIDDEN + lane * 4) = *(uint2*)pk;
}

// ---------------- global mean pool (partial sums + atomics), bf16 input ----------------
__global__ void k_pool(const __hip_bfloat16* __restrict__ h, const int* __restrict__ gstart,
                       const int* __restrict__ gcnt, float* __restrict__ pooled) {
    int g = blockIdx.x, chunk = blockIdx.y, t = threadIdx.x;
    int s = gstart[g], c = gcnt[g];
    int i0 = s + (int)(((long long)c * chunk) / 16);
    int i1 = s + (int)(((long long)c * (chunk + 1)) / 16);
    const unsigned short* hu = (const unsigned short*)h;
    float acc = 0.f;
    for (int i = i0; i < i1; ++i) acc += bf2f(hu[(size_t)i * HIDDEN + t]);
    atomicAdd(&pooled[g * HIDDEN + t], acc);
}

// ---------------- classifier head + softmax (one wave per graph) ----------------
__global__ void k_head(const float* __restrict__ pooled, const int* __restrict__ gcnt,
                       const float* __restrict__ Wc, const float* __restrict__ bc,
                       float* __restrict__ out) {
    int g = blockIdx.x; int l = threadIdx.x;  // 64 threads
    float inv = 1.0f / fmaxf((float)gcnt[g], 1.0f);
    float p[4];
#pragma unroll
    for (int i = 0; i < 4; i++) p[i] = pooled[g * HIDDEN + l + i * 64] * inv;
    __shared__ float logits[N_CLASSES];
#pragma unroll
    for (int j = 0; j < N_CLASSES; j++) {
        float s = 0.f;
#pragma unroll
        for (int i = 0; i < 4; i++) s += p[i] * Wc[(l + i * 64) * N_CLASSES + j];
        for (int o = 32; o > 0; o >>= 1) s += __shfl_down(s, o, 64);
        if (l == 0) logits[j] = s + bc[j];
    }
    __syncthreads();
    if (l == 0) {
        float m = logits[0];
        for (int j = 1; j < N_CLASSES; j++) m = fmaxf(m, logits[j]);
        float e[N_CLASSES]; float sum = 0.f;
        for (int j = 0; j < N_CLASSES; j++) { e[j] = expf(logits[j] - m); sum += e[j]; }
        for (int j = 0; j < N_CLASSES; j++) out[g * N_CLASSES + j] = e[j] / sum;
    }
}

extern "C" void kernel_launch(void* const* d_in, const int* in_sizes, int n_in,
                              void* d_out, int out_size, void* d_ws, size_t ws_size,
                              hipStream_t stream) {
    const float* x     = (const float*)d_in[0];
    const int*   edge  = (const int*)d_in[1];
    const int*   batch = (const int*)d_in[2];
    const float* W1 = (const float*)d_in[3];
    const float* b1 = (const float*)d_in[4];
    const float* W2 = (const float*)d_in[5];
    const float* b2 = (const float*)d_in[6];
    const float* W3 = (const float*)d_in[7];
    const float* b3 = (const float*)d_in[8];
    const float* Wc = (const float*)d_in[9];
    const float* bc = (const float*)d_in[10];
    float* out = (float*)d_out;
    const int* srcp = edge;
    const int* dstp = edge + N_EDGES;

    char* ws = (char*)d_ws;
    size_t off = 0;
    auto alloc = [&](size_t bytes) -> char* {
        char* p = ws + off;
        off += (bytes + 255) & ~(size_t)255;
        return p;
    };
    __hip_bfloat16* hA  = (__hip_bfloat16*)alloc((size_t)N_NODES * HIDDEN * 2);
    __hip_bfloat16* hB  = (__hip_bfloat16*)alloc((size_t)N_NODES * HIDDEN * 2);
    __hip_bfloat16* Wt2 = (__hip_bfloat16*)alloc((size_t)HIDDEN * HIDDEN * 2);
    __hip_bfloat16* Wt3 = (__hip_bfloat16*)alloc((size_t)HIDDEN * HIDDEN * 2);
    int*   deg_cnt  = (int*)alloc((size_t)N_NODES * 4);
    float* dinv     = (float*)alloc((size_t)N_NODES * 4);
    int*   csr_off  = (int*)alloc((size_t)(N_NODES + 1) * 4);
    int*   cursor   = (int*)alloc((size_t)N_NODES * 4);
    int2*  csr_rec  = (int2*)alloc((size_t)E_PAD * 8);
    float4* ax      = (float4*)alloc((size_t)N_NODES * 16);
    int*   gcnt     = (int*)alloc((size_t)N_GRAPHS * 4);
    int*   gstart   = (int*)alloc((size_t)N_GRAPHS * 4);
    float* pooled   = (float*)alloc((size_t)N_GRAPHS * HIDDEN * 4);
    int*   bsum     = (int*)alloc(128 * 4);

    hipMemsetAsync(deg_cnt, 0, (size_t)N_NODES * 4, stream);
    hipMemsetAsync(pooled, 0, (size_t)N_GRAPHS * HIDDEN * 4, stream);

    int eb4 = (N_EDGES / 4 + 255) / 256;   // 4 edges/thread
    int nb  = (N_NODES + 255) / 256;
    int sblocks = (N_NODES + 1023) / 1024;  // 98
    int cb  = (E_PAD + 255) / 256;

    k_deg_hist<<<eb4, 256, 0, stream>>>(dstp, deg_cnt);
    k_graph_bounds<<<1, 64, 0, stream>>>(batch, gstart, gcnt);
    k_dinv<<<nb, 256, 0, stream>>>(deg_cnt, dinv);
    k_scanA<<<sblocks, 256, 0, stream>>>(deg_cnt, csr_off, bsum);
    k_scanB<<<1, 128, 0, stream>>>(bsum, sblocks);
    k_scanC<<<nb, 256, 0, stream>>>(csr_off, bsum, cursor, deg_cnt, csr_rec);
    k_fill<<<eb4, 256, 0, stream>>>(srcp, dstp, cursor, csr_rec);
    k_coef<<<cb, 256, 0, stream>>>(csr_rec, dinv, csr_off + N_NODES);
    k_wprep<<<HIDDEN, HIDDEN, 0, stream>>>(W2, Wt2);
    k_wprep<<<HIDDEN, HIDDEN, 0, stream>>>(W3, Wt3);

    // layer 1 (reassociated): ax = Norm*x; h1 = leaky(ax @ W1 + b1)
    k_agg3<<<nb, 256, 0, stream>>>(x, csr_off, csr_rec, dinv, ax);
    k_l1<<<N_NODES, 256, 0, stream>>>(ax, W1, b1, hA);

    int aggb  = (N_NODES + 3) / 4;
    int gemmb = (N_NODES + 63) / 64;
    // layer 2
    k_gemm_mfma<<<gemmb, 256, 0, stream>>>(hA, Wt2, hB, N_NODES);
    k_agg<<<aggb, 256, 0, stream>>>(hB, b2, csr_off, csr_rec, dinv, hA);
    // layer 3
    k_gemm_mfma<<<gemmb, 256, 0, stream>>>(hA, Wt3, hB, N_NODES);
    k_agg<<<aggb, 256, 0, stream>>>(hB, b3, csr_off, csr_rec, dinv, hA);
    // pool + head
    dim3 pg(N_GRAPHS, 16);
    k_pool<<<pg, 256, 0, stream>>>(hA, gstart, gcnt, pooled);
    k_head<<<N_GRAPHS, 64, 0, stream>>>(pooled, gcnt, Wc, bc, out);
}

// Round 9
// 797.756 us; speedup vs baseline: 1.0847x; 1.0009x over previous
//
#include <hip/hip_runtime.h>
#include <hip/hip_bf16.h>
#include <cstdint>
#include <cstddef>

#define N_NODES   100000
#define N_EDGES   1600000
#define N_GRAPHS  64
#define HIDDEN    256
#define N_CLASSES 10
#define NEG_SLOPE 0.01f

#define E_PAD   (N_EDGES + 8 * N_NODES)
#define CSTRIDE 16   // one counter per 64B line

typedef __attribute__((ext_vector_type(8))) short bfrag8;   // 8 bf16 (4 VGPRs)
typedef __attribute__((ext_vector_type(4))) float f32x4;    // MFMA C/D

__device__ __forceinline__ float bf2f(unsigned short u) {
    return __uint_as_float(((unsigned int)u) << 16);
}

// ---------------- degree histogram (4 edges/thread, line-padded counters) ----------------
__global__ void k_deg_hist(const int* __restrict__ dst, int* __restrict__ cnt) {
    int e = (blockIdx.x * 256 + threadIdx.x) * 4;
    if (e >= N_EDGES) return;
    int4 d4 = *(const int4*)(dst + e);
    atomicAdd(&cnt[d4.x * CSTRIDE], 1);
    atomicAdd(&cnt[d4.y * CSTRIDE], 1);
    atomicAdd(&cnt[d4.z * CSTRIDE], 1);
    atomicAdd(&cnt[d4.w * CSTRIDE], 1);
}

// ---------------- graph boundaries via binary search (batch is sorted) ----------------
__global__ void k_graph_bounds(const int* __restrict__ batch,
                               int* __restrict__ gstart, int* __restrict__ gcnt) {
    int g = threadIdx.x;  // 0..63
    int lo = 0, hi = N_NODES;
    while (lo < hi) { int mid = (lo + hi) >> 1; if (batch[mid] < g) lo = mid + 1; else hi = mid; }
    __shared__ int sh[N_GRAPHS + 1];
    sh[g] = lo;
    if (g == 0) sh[N_GRAPHS] = N_NODES;
    __syncthreads();
    gstart[g] = sh[g];
    gcnt[g]   = sh[g + 1] - sh[g];
}

__global__ void k_dinv(const int* __restrict__ cnt, float* __restrict__ dinv) {
    int i = blockIdx.x * 256 + threadIdx.x;
    if (i < N_NODES) dinv[i] = rsqrtf((float)cnt[i * CSTRIDE] + 1.0f);
}

// ---------------- exclusive scan of PADDED degree counts (CSR offsets) ----------------
// degrees rounded up to multiple of 8 so the agg loop is exact 8-wide
__global__ void k_scanA(const int* __restrict__ cnt, int* __restrict__ out, int* __restrict__ bsum) {
    __shared__ int sh[256];
    int tid = threadIdx.x;
    int base = blockIdx.x * 1024 + tid * 4;
    int v[4]; int s = 0;
#pragma unroll
    for (int i = 0; i < 4; i++) {
        int idx = base + i;
        v[i] = (idx < N_NODES) ? ((cnt[idx * CSTRIDE] + 7) & ~7) : 0;
        s += v[i];
    }
    sh[tid] = s; __syncthreads();
    for (int off = 1; off < 256; off <<= 1) {
        int t = (tid >= off) ? sh[tid - off] : 0;
        __syncthreads();
        sh[tid] += t;
        __syncthreads();
    }
    int excl = sh[tid] - s;
    if (tid == 255) bsum[blockIdx.x] = sh[255];
#pragma unroll
    for (int i = 0; i < 4; i++) { int idx = base + i; if (idx < N_NODES) out[idx] = excl; excl += v[i]; }
}

__global__ void k_scanB(int* __restrict__ bsum, int nb) {
    __shared__ int sh[128];
    int tid = threadIdx.x;
    int v = (tid < nb) ? bsum[tid] : 0;
    sh[tid] = v; __syncthreads();
    for (int off = 1; off < 128; off <<= 1) {
        int t = (tid >= off) ? sh[tid - off] : 0;
        __syncthreads();
        sh[tid] += t;
        __syncthreads();
    }
    if (tid < nb) bsum[tid] = sh[tid] - v;  // exclusive
}

// finalize offsets + init line-padded cursor + sentinel records into padding slots
__global__ void k_scanC(int* __restrict__ off_arr, const int* __restrict__ bsum,
                        int* __restrict__ cursor, const int* __restrict__ cnt,
                        int2* __restrict__ rec) {
    int i = blockIdx.x * 256 + threadIdx.x;
    if (i < N_NODES) {
        int v = off_arr[i] + bsum[i >> 10];
        off_arr[i] = v;
        cursor[i * CSTRIDE] = v;
        int c  = cnt[i * CSTRIDE];
        int cp = (c + 7) & ~7;
        for (int p = v + c; p < v + cp; ++p) rec[p] = make_int2(-1, 0);
        if (i == N_NODES - 1) off_arr[N_NODES] = v + cp;
    }
}

// ---------------- CSR fill: 8 edges/thread, line-padded cursor, {src,dst} records ----------------
__global__ void k_fill(const int* __restrict__ src, const int* __restrict__ dst,
                       int* __restrict__ cursor, int2* __restrict__ rec) {
    int e = (blockIdx.x * 256 + threadIdx.x) * 8;
    if (e >= N_EDGES) return;
    int4 da = *(const int4*)(dst + e);
    int4 db = *(const int4*)(dst + e + 4);
    int4 sa = *(const int4*)(src + e);
    int4 sb = *(const int4*)(src + e + 4);
    int p0 = atomicAdd(&cursor[da.x * CSTRIDE], 1);
    int p1 = atomicAdd(&cursor[da.y * CSTRIDE], 1);
    int p2 = atomicAdd(&cursor[da.z * CSTRIDE], 1);
    int p3 = atomicAdd(&cursor[da.w * CSTRIDE], 1);
    int p4 = atomicAdd(&cursor[db.x * CSTRIDE], 1);
    int p5 = atomicAdd(&cursor[db.y * CSTRIDE], 1);
    int p6 = atomicAdd(&cursor[db.z * CSTRIDE], 1);
    int p7 = atomicAdd(&cursor[db.w * CSTRIDE], 1);
    rec[p0] = make_int2(sa.x, da.x);
    rec[p1] = make_int2(sa.y, da.y);
    rec[p2] = make_int2(sa.z, da.z);
    rec[p3] = make_int2(sa.w, da.w);
    rec[p4] = make_int2(sb.x, db.x);
    rec[p5] = make_int2(sb.y, db.y);
    rec[p6] = make_int2(sb.z, db.z);
    rec[p7] = make_int2(sb.w, db.w);
}

// ---------------- coef pass: rewrite records {src,dst} -> {src,coef} (fully linear) ----------------
__global__ void k_coef(int2* __restrict__ rec, const float* __restrict__ dinv,
                       const int* __restrict__ off_end) {
    int p = blockIdx.x * 256 + threadIdx.x;
    if (p >= off_end[0]) return;
    int2 r = rec[p];
    if (r.x < 0) {
        rec[p] = make_int2(0, 0);  // padding: src=0, coef=0
    } else {
        float c = dinv[r.x] * dinv[r.y];
        rec[p] = make_int2(r.x, __float_as_int(c));
    }
}

// ---------------- weight prep: W[k][n] fp32 -> Wt[n][k] bf16 ----------------
__global__ void k_wprep(const float* __restrict__ W, __hip_bfloat16* __restrict__ Wt) {
    int n = blockIdx.x; int k = threadIdx.x;  // 256 x 256
    Wt[n * HIDDEN + k] = __float2bfloat16(W[k * HIDDEN + n]);
}

// ---------------- layer-1 reassociated: ax = Norm * x  (3 features, exact) ----------------
__global__ void k_agg3(const float* __restrict__ x, const int* __restrict__ off,
                       const int2* __restrict__ rec, const float* __restrict__ dinv,
                       float4* __restrict__ ax) {
    int i = blockIdx.x * 256 + threadIdx.x;
    if (i >= N_NODES) return;
    float di = dinv[i];
    float selfc = di * di;
    float a0 = x[i * 3 + 0] * selfc, a1 = x[i * 3 + 1] * selfc, a2 = x[i * 3 + 2] * selfc;
    int e = off[i], e1 = off[i + 1];
    for (; e < e1; e += 4) {
        const int4* rp = (const int4*)(rec + e);
        int4 r01 = rp[0];  // {s0, c0, s1, c1}
        int4 r23 = rp[1];  // {s2, c2, s3, c3}
        int s0 = r01.x, s1 = r01.z, s2 = r23.x, s3 = r23.z;
        float c0 = __int_as_float(r01.y), c1 = __int_as_float(r01.w);
        float c2 = __int_as_float(r23.y), c3 = __int_as_float(r23.w);
        a0 += c0 * x[s0 * 3 + 0] + c1 * x[s1 * 3 + 0] + c2 * x[s2 * 3 + 0] + c3 * x[s3 * 3 + 0];
        a1 += c0 * x[s0 * 3 + 1] + c1 * x[s1 * 3 + 1] + c2 * x[s2 * 3 + 1] + c3 * x[s3 * 3 + 1];
        a2 += c0 * x[s0 * 3 + 2] + c1 * x[s1 * 3 + 2] + c2 * x[s2 * 3 + 2] + c3 * x[s3 * 3 + 2];
    }
    ax[i] = make_float4(a0, a1, a2, 0.f);
}

// h1 = leaky(ax @ W1 + b1), bf16 out
__global__ void k_l1(const float4* __restrict__ ax, const float* __restrict__ W1,
                     const float* __restrict__ b1, __hip_bfloat16* __restrict__ out) {
    int node = blockIdx.x; int c = threadIdx.x;
    float4 a = ax[node];
    float v = a.x * W1[c] + a.y * W1[HIDDEN + c] + a.z * W1[2 * HIDDEN + c] + b1[c];
    v = v >= 0.f ? v : NEG_SLOPE * v;
    out[(size_t)node * HIDDEN + c] = __float2bfloat16(v);
}

// ---------------- MFMA GEMM with LDS-staged Wt ----------------
__global__ __launch_bounds__(256) void k_gemm_mfma(const __hip_bfloat16* __restrict__ A,
                                                   const __hip_bfloat16* __restrict__ Wt,
                                                   __hip_bfloat16* __restrict__ C, int M) {
    __shared__ short Bs[256 * 40];  // 20 KB
    int tid = threadIdx.x;
    int wv = tid >> 6, lane = tid & 63;
    int quad = lane >> 4, r = lane & 15;
    int m0 = blockIdx.x * 64 + wv * 16;
    int arow = m0 + r; if (arow >= M) arow = M - 1;
    const short* Ab = (const short*)A + (size_t)arow * HIDDEN + quad * 8;

    bfrag8 af[8];
#pragma unroll
    for (int c = 0; c < 8; ++c) af[c] = *(const bfrag8*)(Ab + c * 32);

    f32x4 acc[16];
#pragma unroll
    for (int i = 0; i < 16; i++) acc[i] = (f32x4){0.f, 0.f, 0.f, 0.f};

    const float4* wsrc = (const float4*)((const short*)Wt + (size_t)tid * HIDDEN);  // row n=tid
    float4 st[4];
#pragma unroll
    for (int i = 0; i < 4; ++i) st[i] = wsrc[i];  // chunk 0

#pragma unroll
    for (int c = 0; c < 8; ++c) {
        __syncthreads();
        float4* bdst = (float4*)(Bs + tid * 40);
#pragma unroll
        for (int i = 0; i < 4; ++i) bdst[i] = st[i];
        __syncthreads();
        if (c < 7) {
#pragma unroll
            for (int i = 0; i < 4; ++i) st[i] = wsrc[(c + 1) * 4 + i];
        }
#pragma unroll
        for (int nt = 0; nt < 16; ++nt) {
            bfrag8 b = *(const bfrag8*)(Bs + (nt * 16 + r) * 40 + quad * 8);
            acc[nt] = __builtin_amdgcn_mfma_f32_16x16x32_bf16(af[c], b, acc[nt], 0, 0, 0);
        }
    }
#pragma unroll
    for (int nt = 0; nt < 16; ++nt) {
#pragma unroll
        for (int i = 0; i < 4; ++i) {
            int row = m0 + quad * 4 + i;
            if (row < M) C[(size_t)row * HIDDEN + nt * 16 + r] = __float2bfloat16(acc[nt][i]);
        }
    }
}

// ---------------- fused aggregation + self-loop + bias + leaky-relu ----------------
// one wave per node; bf16 rows; padded CSR (multiple of 8) -> branch-free 8-wide loop
__global__ __launch_bounds__(256) void k_agg(const __hip_bfloat16* __restrict__ h,
                                             const float* __restrict__ bias,
                                             const int* __restrict__ off, const int2* __restrict__ rec,
                                             const float* __restrict__ dinv,
                                             __hip_bfloat16* __restrict__ out) {
    int node = (blockIdx.x * 256 + threadIdx.x) >> 6;
    int lane = threadIdx.x & 63;
    if (node >= N_NODES) return;
    float di = dinv[node];
    float selfc = di * di;
    ushort4 hv = ((const ushort4*)(h + (size_t)node * HIDDEN))[lane];
    float4 bv = ((const float4*)bias)[lane];
    float4 acc = make_float4(bv.x + bf2f(hv.x) * selfc, bv.y + bf2f(hv.y) * selfc,
                             bv.z + bf2f(hv.z) * selfc, bv.w + bf2f(hv.w) * selfc);
    int e = off[node], e1 = off[node + 1];
    for (; e < e1; e += 8) {
        const int4* rp = (const int4*)(rec + e);
        int4 ra = rp[0];  // {s0,c0,s1,c1}
        int4 rb = rp[1];  // {s2,c2,s3,c3}
        int4 rc = rp[2];  // {s4,c4,s5,c5}
        int4 rd = rp[3];  // {s6,c6,s7,c7}
        ushort4 v0 = ((const ushort4*)(h + (size_t)ra.x * HIDDEN))[lane];
        ushort4 v1 = ((const ushort4*)(h + (size_t)ra.z * HIDDEN))[lane];
        ushort4 v2 = ((const ushort4*)(h + (size_t)rb.x * HIDDEN))[lane];
        ushort4 v3 = ((const ushort4*)(h + (size_t)rb.z * HIDDEN))[lane];
        ushort4 v4 = ((const ushort4*)(h + (size_t)rc.x * HIDDEN))[lane];
        ushort4 v5 = ((const ushort4*)(h + (size_t)rc.z * HIDDEN))[lane];
        ushort4 v6 = ((const ushort4*)(h + (size_t)rd.x * HIDDEN))[lane];
        ushort4 v7 = ((const ushort4*)(h + (size_t)rd.z * HIDDEN))[lane];
        float c0 = __int_as_float(ra.y), c1 = __int_as_float(ra.w);
        float c2 = __int_as_float(rb.y), c3 = __int_as_float(rb.w);
        float c4 = __int_as_float(rc.y), c5 = __int_as_float(rc.w);
        float c6 = __int_as_float(rd.y), c7 = __int_as_float(rd.w);
        acc.x += c0 * bf2f(v0.x) + c1 * bf2f(v1.x) + c2 * bf2f(v2.x) + c3 * bf2f(v3.x)
               + c4 * bf2f(v4.x) + c5 * bf2f(v5.x) + c6 * bf2f(v6.x) + c7 * bf2f(v7.x);
        acc.y += c0 * bf2f(v0.y) + c1 * bf2f(v1.y) + c2 * bf2f(v2.y) + c3 * bf2f(v3.y)
               + c4 * bf2f(v4.y) + c5 * bf2f(v5.y) + c6 * bf2f(v6.y) + c7 * bf2f(v7.y);
        acc.z += c0 * bf2f(v0.z) + c1 * bf2f(v1.z) + c2 * bf2f(v2.z) + c3 * bf2f(v3.z)
               + c4 * bf2f(v4.z) + c5 * bf2f(v5.z) + c6 * bf2f(v6.z) + c7 * bf2f(v7.z);
        acc.w += c0 * bf2f(v0.w) + c1 * bf2f(v1.w) + c2 * bf2f(v2.w) + c3 * bf2f(v3.w)
               + c4 * bf2f(v4.w) + c5 * bf2f(v5.w) + c6 * bf2f(v6.w) + c7 * bf2f(v7.w);
    }
    acc.x = acc.x >= 0.f ? acc.x : NEG_SLOPE * acc.x;
    acc.y = acc.y >= 0.f ? acc.y : NEG_SLOPE * acc.y;
    acc.z = acc.z >= 0.f ? acc.z : NEG_SLOPE * acc.z;
    acc.w = acc.w >= 0.f ? acc.w : NEG_SLOPE * acc.w;
    __hip_bfloat16 pk[4] = {__float2bfloat16(acc.x), __float2bfloat16(acc.y),
                            __float2bfloat16(acc.z), __float2bfloat16(acc.w)};
    *(uint2*)(out + (size_t)node * HIDDEN + lane * 4) = *(uint2*)pk;
}

// ---------------- global mean pool (partial sums + atomics), bf16 input ----------------
__global__ void k_pool(const __hip_bfloat16* __restrict__ h, const int* __restrict__ gstart,
                       const int* __restrict__ gcnt, float* __restrict__ pooled) {
    int g = blockIdx.x, chunk = blockIdx.y, t = threadIdx.x;
    int s = gstart[g], c = gcnt[g];
    int i0 = s + (int)(((long long)c * chunk) / 16);
    int i1 = s + (int)(((long long)c * (chunk + 1)) / 16);
    const unsigned short* hu = (const unsigned short*)h;
    float acc = 0.f;
    for (int i = i0; i < i1; ++i) acc += bf2f(hu[(size_t)i * HIDDEN + t]);
    atomicAdd(&pooled[g * HIDDEN + t], acc);
}

// ---------------- classifier head + softmax (one wave per graph) ----------------
__global__ void k_head(const float* __restrict__ pooled, const int* __restrict__ gcnt,
                       const float* __restrict__ Wc, const float* __restrict__ bc,
                       float* __restrict__ out) {
    int g = blockIdx.x; int l = threadIdx.x;  // 64 threads
    float inv = 1.0f / fmaxf((float)gcnt[g], 1.0f);
    float p[4];
#pragma unroll
    for (int i = 0; i < 4; i++) p[i] = pooled[g * HIDDEN + l + i * 64] * inv;
    __shared__ float logits[N_CLASSES];
#pragma unroll
    for (int j = 0; j < N_CLASSES; j++) {
        float s = 0.f;
#pragma unroll
        for (int i = 0; i < 4; i++) s += p[i] * Wc[(l + i * 64) * N_CLASSES + j];
        for (int o = 32; o > 0; o >>= 1) s += __shfl_down(s, o, 64);
        if (l == 0) logits[j] = s + bc[j];
    }
    __syncthreads();
    if (l == 0) {
        float m = logits[0];
        for (int j = 1; j < N_CLASSES; j++) m = fmaxf(m, logits[j]);
        float e[N_CLASSES]; float sum = 0.f;
        for (int j = 0; j < N_CLASSES; j++) { e[j] = expf(logits[j] - m); sum += e[j]; }
        for (int j = 0; j < N_CLASSES; j++) out[g * N_CLASSES + j] = e[j] / sum;
    }
}

extern "C" void kernel_launch(void* const* d_in, const int* in_sizes, int n_in,
                              void* d_out, int out_size, void* d_ws, size_t ws_size,
                              hipStream_t stream) {
    const float* x     = (const float*)d_in[0];
    const int*   edge  = (const int*)d_in[1];
    const int*   batch = (const int*)d_in[2];
    const float* W1 = (const float*)d_in[3];
    const float* b1 = (const float*)d_in[4];
    const float* W2 = (const float*)d_in[5];
    const float* b2 = (const float*)d_in[6];
    const float* W3 = (const float*)d_in[7];
    const float* b3 = (const float*)d_in[8];
    const float* Wc = (const float*)d_in[9];
    const float* bc = (const float*)d_in[10];
    float* out = (float*)d_out;
    const int* srcp = edge;
    const int* dstp = edge + N_EDGES;

    char* ws = (char*)d_ws;
    size_t off = 0;
    auto alloc = [&](size_t bytes) -> char* {
        char* p = ws + off;
        off += (bytes + 255) & ~(size_t)255;
        return p;
    };
    __hip_bfloat16* hA  = (__hip_bfloat16*)alloc((size_t)N_NODES * HIDDEN * 2);
    __hip_bfloat16* hB  = (__hip_bfloat16*)alloc((size_t)N_NODES * HIDDEN * 2);
    __hip_bfloat16* Wt2 = (__hip_bfloat16*)alloc((size_t)HIDDEN * HIDDEN * 2);
    __hip_bfloat16* Wt3 = (__hip_bfloat16*)alloc((size_t)HIDDEN * HIDDEN * 2);
    int*   deg_cnt  = (int*)alloc((size_t)N_NODES * CSTRIDE * 4);  // line-padded
    float* dinv     = (float*)alloc((size_t)N_NODES * 4);
    int*   csr_off  = (int*)alloc((size_t)(N_NODES + 1) * 4);
    int*   cursor   = (int*)alloc((size_t)N_NODES * CSTRIDE * 4);  // line-padded
    int2*  csr_rec  = (int2*)alloc((size_t)E_PAD * 8);
    float4* ax      = (float4*)alloc((size_t)N_NODES * 16);
    int*   gcnt     = (int*)alloc((size_t)N_GRAPHS * 4);
    int*   gstart   = (int*)alloc((size_t)N_GRAPHS * 4);
    float* pooled   = (float*)alloc((size_t)N_GRAPHS * HIDDEN * 4);
    int*   bsum     = (int*)alloc(128 * 4);

    hipMemsetAsync(deg_cnt, 0, (size_t)N_NODES * CSTRIDE * 4, stream);
    hipMemsetAsync(pooled, 0, (size_t)N_GRAPHS * HIDDEN * 4, stream);

    int eb4 = (N_EDGES / 4 + 255) / 256;   // 4 edges/thread
    int eb8 = (N_EDGES / 8 + 255) / 256;   // 8 edges/thread
    int nb  = (N_NODES + 255) / 256;
    int sblocks = (N_NODES + 1023) / 1024;  // 98
    int cb  = (E_PAD + 255) / 256;

    k_deg_hist<<<eb4, 256, 0, stream>>>(dstp, deg_cnt);
    k_graph_bounds<<<1, 64, 0, stream>>>(batch, gstart, gcnt);
    k_dinv<<<nb, 256, 0, stream>>>(deg_cnt, dinv);
    k_scanA<<<sblocks, 256, 0, stream>>>(deg_cnt, csr_off, bsum);
    k_scanB<<<1, 128, 0, stream>>>(bsum, sblocks);
    k_scanC<<<nb, 256, 0, stream>>>(csr_off, bsum, cursor, deg_cnt, csr_rec);
    k_fill<<<eb8, 256, 0, stream>>>(srcp, dstp, cursor, csr_rec);
    k_coef<<<cb, 256, 0, stream>>>(csr_rec, dinv, csr_off + N_NODES);
    k_wprep<<<HIDDEN, HIDDEN, 0, stream>>>(W2, Wt2);
    k_wprep<<<HIDDEN, HIDDEN, 0, stream>>>(W3, Wt3);

    // layer 1 (reassociated): ax = Norm*x; h1 = leaky(ax @ W1 + b1)
    k_agg3<<<nb, 256, 0, stream>>>(x, csr_off, csr_rec, dinv, ax);
    k_l1<<<N_NODES, 256, 0, stream>>>(ax, W1, b1, hA);

    int aggb  = (N_NODES + 3) / 4;
    int gemmb = (N_NODES + 63) / 64;
    // layer 2
    k_gemm_mfma<<<gemmb, 256, 0, stream>>>(hA, Wt2, hB, N_NODES);
    k_agg<<<aggb, 256, 0, stream>>>(hB, b2, csr_off, csr_rec, dinv, hA);
    // layer 3
    k_gemm_mfma<<<gemmb, 256, 0, stream>>>(hA, Wt3, hB, N_NODES);
    k_agg<<<aggb, 256, 0, stream>>>(hB, b3, csr_off, csr_rec, dinv, hA);
    // pool + head
    dim3 pg(N_GRAPHS, 16);
    k_pool<<<pg, 256, 0, stream>>>(hA, gstart, gcnt, pooled);
    k_head<<<N_GRAPHS, 64, 0, stream>>>(pooled, gcnt, Wc, bc, out);
}

// Round 10
// 739.568 us; speedup vs baseline: 1.1701x; 1.0787x over previous
//
#include <hip/hip_runtime.h>
#include <hip/hip_bf16.h>
#include <cstdint>
#include <cstddef>

#define N_NODES   100000
#define N_EDGES   1600000
#define N_GRAPHS  64
#define HIDDEN    256
#define N_CLASSES 10
#define NEG_SLOPE 0.01f

#define E_PAD    (N_EDGES + 8 * N_NODES)
#define N_RANGES 8
#define R_SIZE   ((N_NODES + N_RANGES - 1) / N_RANGES)   // 12500
#define CHUNK    2048

typedef __attribute__((ext_vector_type(8))) short bfrag8;   // 8 bf16 (4 VGPRs)
typedef __attribute__((ext_vector_type(4))) float f32x4;    // MFMA C/D

__device__ __forceinline__ float bf2f(unsigned short u) {
    return __uint_as_float(((unsigned int)u) << 16);
}

// ---------------- degree histogram (4 edges/thread) ----------------
__global__ void k_deg_hist(const int* __restrict__ dst, int* __restrict__ cnt) {
    int e = (blockIdx.x * 256 + threadIdx.x) * 4;
    if (e >= N_EDGES) return;
    int4 d4 = *(const int4*)(dst + e);
    atomicAdd(&cnt[d4.x], 1);
    atomicAdd(&cnt[d4.y], 1);
    atomicAdd(&cnt[d4.z], 1);
    atomicAdd(&cnt[d4.w], 1);
}

// ---------------- graph boundaries via binary search (batch is sorted) ----------------
__global__ void k_graph_bounds(const int* __restrict__ batch,
                               int* __restrict__ gstart, int* __restrict__ gcnt) {
    int g = threadIdx.x;  // 0..63
    int lo = 0, hi = N_NODES;
    while (lo < hi) { int mid = (lo + hi) >> 1; if (batch[mid] < g) lo = mid + 1; else hi = mid; }
    __shared__ int sh[N_GRAPHS + 1];
    sh[g] = lo;
    if (g == 0) sh[N_GRAPHS] = N_NODES;
    __syncthreads();
    gstart[g] = sh[g];
    gcnt[g]   = sh[g + 1] - sh[g];
}

__global__ void k_dinv(const int* __restrict__ cnt, float* __restrict__ dinv) {
    int i = blockIdx.x * 256 + threadIdx.x;
    if (i < N_NODES) dinv[i] = rsqrtf((float)cnt[i] + 1.0f);
}

// ---------------- exclusive scan of PADDED degree counts (CSR offsets) ----------------
// degrees rounded up to multiple of 8 -> node segments are 64B-line-aligned
__global__ void k_scanA(const int* __restrict__ cnt, int* __restrict__ out, int* __restrict__ bsum) {
    __shared__ int sh[256];
    int tid = threadIdx.x;
    int base = blockIdx.x * 1024 + tid * 4;
    int v[4]; int s = 0;
#pragma unroll
    for (int i = 0; i < 4; i++) {
        int idx = base + i;
        v[i] = (idx < N_NODES) ? ((cnt[idx] + 7) & ~7) : 0;
        s += v[i];
    }
    sh[tid] = s; __syncthreads();
    for (int off = 1; off < 256; off <<= 1) {
        int t = (tid >= off) ? sh[tid - off] : 0;
        __syncthreads();
        sh[tid] += t;
        __syncthreads();
    }
    int excl = sh[tid] - s;
    if (tid == 255) bsum[blockIdx.x] = sh[255];
#pragma unroll
    for (int i = 0; i < 4; i++) { int idx = base + i; if (idx < N_NODES) out[idx] = excl; excl += v[i]; }
}

__global__ void k_scanB(int* __restrict__ bsum, int nb) {
    __shared__ int sh[128];
    int tid = threadIdx.x;
    int v = (tid < nb) ? bsum[tid] : 0;
    sh[tid] = v; __syncthreads();
    for (int off = 1; off < 128; off <<= 1) {
        int t = (tid >= off) ? sh[tid - off] : 0;
        __syncthreads();
        sh[tid] += t;
        __syncthreads();
    }
    if (tid < nb) bsum[tid] = sh[tid] - v;  // exclusive
}

// finalize offsets + init cursor + final {0,0.0} records into padding slots
__global__ void k_scanC(int* __restrict__ off_arr, const int* __restrict__ bsum,
                        int* __restrict__ cursor, const int* __restrict__ cnt,
                        int2* __restrict__ rec) {
    int i = blockIdx.x * 256 + threadIdx.x;
    if (i < N_NODES) {
        int v = off_arr[i] + bsum[i >> 10];
        off_arr[i] = v;
        cursor[i]  = v;
        int c  = cnt[i];
        int cp = (c + 7) & ~7;
        for (int p = v + c; p < v + cp; ++p) rec[p] = make_int2(0, 0);
        if (i == N_NODES - 1) off_arr[N_NODES] = v + cp;
    }
}

// ---------------- XCD-partitioned CSR fill, coef fused ----------------
// block b: range r = b&7 (dst in [r*R_SIZE,(r+1)*R_SIZE)), edge chunk b>>3.
// Under round-robin block->XCD dispatch, each range's rec/cursor slice stays
// in ONE XCD's L2 -> rec lines written once. Correct regardless of mapping.
__global__ __launch_bounds__(256) void k_fill(const int* __restrict__ src, const int* __restrict__ dst,
                                              const float* __restrict__ dinv,
                                              int* __restrict__ cursor, int2* __restrict__ rec) {
    int b = blockIdx.x;
    int r = b & (N_RANGES - 1);
    int lo = r * R_SIZE, hi = lo + R_SIZE;
    int e0 = (b >> 3) * CHUNK + threadIdx.x * 8;
    if (e0 >= N_EDGES) return;
    if (e0 + 8 <= N_EDGES) {
        int4 da = *(const int4*)(dst + e0);
        int4 db = *(const int4*)(dst + e0 + 4);
        int d[8] = {da.x, da.y, da.z, da.w, db.x, db.y, db.z, db.w};
#pragma unroll
        for (int j = 0; j < 8; ++j) {
            if (d[j] >= lo && d[j] < hi) {
                int s = src[e0 + j];
                float c = dinv[s] * dinv[d[j]];
                int p = atomicAdd(&cursor[d[j]], 1);
                rec[p] = make_int2(s, __float_as_int(c));
            }
        }
    } else {
        for (int j = 0; j < 8 && e0 + j < N_EDGES; ++j) {
            int dj = dst[e0 + j];
            if (dj >= lo && dj < hi) {
                int s = src[e0 + j];
                float c = dinv[s] * dinv[dj];
                int p = atomicAdd(&cursor[dj], 1);
                rec[p] = make_int2(s, __float_as_int(c));
            }
        }
    }
}

// ---------------- weight prep: W[k][n] fp32 -> Wt[n][k] bf16 ----------------
__global__ void k_wprep(const float* __restrict__ W, __hip_bfloat16* __restrict__ Wt) {
    int n = blockIdx.x; int k = threadIdx.x;  // 256 x 256
    Wt[n * HIDDEN + k] = __float2bfloat16(W[k * HIDDEN + n]);
}

// ---------------- layer-1 reassociated: ax = Norm * x  (3 features, exact) ----------------
__global__ void k_agg3(const float* __restrict__ x, const int* __restrict__ off,
                       const int2* __restrict__ rec, const float* __restrict__ dinv,
                       float4* __restrict__ ax) {
    int i = blockIdx.x * 256 + threadIdx.x;
    if (i >= N_NODES) return;
    float di = dinv[i];
    float selfc = di * di;
    float a0 = x[i * 3 + 0] * selfc, a1 = x[i * 3 + 1] * selfc, a2 = x[i * 3 + 2] * selfc;
    int e = off[i], e1 = off[i + 1];
    for (; e < e1; e += 4) {
        const int4* rp = (const int4*)(rec + e);
        int4 r01 = rp[0];  // {s0, c0, s1, c1}
        int4 r23 = rp[1];  // {s2, c2, s3, c3}
        int s0 = r01.x, s1 = r01.z, s2 = r23.x, s3 = r23.z;
        float c0 = __int_as_float(r01.y), c1 = __int_as_float(r01.w);
        float c2 = __int_as_float(r23.y), c3 = __int_as_float(r23.w);
        a0 += c0 * x[s0 * 3 + 0] + c1 * x[s1 * 3 + 0] + c2 * x[s2 * 3 + 0] + c3 * x[s3 * 3 + 0];
        a1 += c0 * x[s0 * 3 + 1] + c1 * x[s1 * 3 + 1] + c2 * x[s2 * 3 + 1] + c3 * x[s3 * 3 + 1];
        a2 += c0 * x[s0 * 3 + 2] + c1 * x[s1 * 3 + 2] + c2 * x[s2 * 3 + 2] + c3 * x[s3 * 3 + 2];
    }
    ax[i] = make_float4(a0, a1, a2, 0.f);
}

// h1 = leaky(ax @ W1 + b1), bf16 out
__global__ void k_l1(const float4* __restrict__ ax, const float* __restrict__ W1,
                     const float* __restrict__ b1, __hip_bfloat16* __restrict__ out) {
    int node = blockIdx.x; int c = threadIdx.x;
    float4 a = ax[node];
    float v = a.x * W1[c] + a.y * W1[HIDDEN + c] + a.z * W1[2 * HIDDEN + c] + b1[c];
    v = v >= 0.f ? v : NEG_SLOPE * v;
    out[(size_t)node * HIDDEN + c] = __float2bfloat16(v);
}

// ---------------- MFMA GEMM with LDS-staged Wt ----------------
__global__ __launch_bounds__(256) void k_gemm_mfma(const __hip_bfloat16* __restrict__ A,
                                                   const __hip_bfloat16* __restrict__ Wt,
                                                   __hip_bfloat16* __restrict__ C, int M) {
    __shared__ short Bs[256 * 40];  // 20 KB
    int tid = threadIdx.x;
    int wv = tid >> 6, lane = tid & 63;
    int quad = lane >> 4, r = lane & 15;
    int m0 = blockIdx.x * 64 + wv * 16;
    int arow = m0 + r; if (arow >= M) arow = M - 1;
    const short* Ab = (const short*)A + (size_t)arow * HIDDEN + quad * 8;

    bfrag8 af[8];
#pragma unroll
    for (int c = 0; c < 8; ++c) af[c] = *(const bfrag8*)(Ab + c * 32);

    f32x4 acc[16];
#pragma unroll
    for (int i = 0; i < 16; i++) acc[i] = (f32x4){0.f, 0.f, 0.f, 0.f};

    const float4* wsrc = (const float4*)((const short*)Wt + (size_t)tid * HIDDEN);  // row n=tid
    float4 st[4];
#pragma unroll
    for (int i = 0; i < 4; ++i) st[i] = wsrc[i];  // chunk 0

#pragma unroll
    for (int c = 0; c < 8; ++c) {
        __syncthreads();
        float4* bdst = (float4*)(Bs + tid * 40);
#pragma unroll
        for (int i = 0; i < 4; ++i) bdst[i] = st[i];
        __syncthreads();
        if (c < 7) {
#pragma unroll
            for (int i = 0; i < 4; ++i) st[i] = wsrc[(c + 1) * 4 + i];
        }
#pragma unroll
        for (int nt = 0; nt < 16; ++nt) {
            bfrag8 b = *(const bfrag8*)(Bs + (nt * 16 + r) * 40 + quad * 8);
            acc[nt] = __builtin_amdgcn_mfma_f32_16x16x32_bf16(af[c], b, acc[nt], 0, 0, 0);
        }
    }
#pragma unroll
    for (int nt = 0; nt < 16; ++nt) {
#pragma unroll
        for (int i = 0; i < 4; ++i) {
            int row = m0 + quad * 4 + i;
            if (row < M) C[(size_t)row * HIDDEN + nt * 16 + r] = __float2bfloat16(acc[nt][i]);
        }
    }
}

// ---------------- fused aggregation + self-loop + bias + leaky-relu ----------------
// one wave per node; bf16 rows; padded CSR (multiple of 8) -> branch-free 8-wide loop
__global__ __launch_bounds__(256) void k_agg(const __hip_bfloat16* __restrict__ h,
                                             const float* __restrict__ bias,
                                             const int* __restrict__ off, const int2* __restrict__ rec,
                                             const float* __restrict__ dinv,
                                             __hip_bfloat16* __restrict__ out) {
    int node = (blockIdx.x * 256 + threadIdx.x) >> 6;
    int lane = threadIdx.x & 63;
    if (node >= N_NODES) return;
    float di = dinv[node];
    float selfc = di * di;
    ushort4 hv = ((const ushort4*)(h + (size_t)node * HIDDEN))[lane];
    float4 bv = ((const float4*)bias)[lane];
    float4 acc = make_float4(bv.x + bf2f(hv.x) * selfc, bv.y + bf2f(hv.y) * selfc,
                             bv.z + bf2f(hv.z) * selfc, bv.w + bf2f(hv.w) * selfc);
    int e = off[node], e1 = off[node + 1];
    for (; e < e1; e += 8) {
        const int4* rp = (const int4*)(rec + e);
        int4 ra = rp[0];  // {s0,c0,s1,c1}
        int4 rb = rp[1];  // {s2,c2,s3,c3}
        int4 rc = rp[2];  // {s4,c4,s5,c5}
        int4 rd = rp[3];  // {s6,c6,s7,c7}
        ushort4 v0 = ((const ushort4*)(h + (size_t)ra.x * HIDDEN))[lane];
        ushort4 v1 = ((const ushort4*)(h + (size_t)ra.z * HIDDEN))[lane];
        ushort4 v2 = ((const ushort4*)(h + (size_t)rb.x * HIDDEN))[lane];
        ushort4 v3 = ((const ushort4*)(h + (size_t)rb.z * HIDDEN))[lane];
        ushort4 v4 = ((const ushort4*)(h + (size_t)rc.x * HIDDEN))[lane];
        ushort4 v5 = ((const ushort4*)(h + (size_t)rc.z * HIDDEN))[lane];
        ushort4 v6 = ((const ushort4*)(h + (size_t)rd.x * HIDDEN))[lane];
        ushort4 v7 = ((const ushort4*)(h + (size_t)rd.z * HIDDEN))[lane];
        float c0 = __int_as_float(ra.y), c1 = __int_as_float(ra.w);
        float c2 = __int_as_float(rb.y), c3 = __int_as_float(rb.w);
        float c4 = __int_as_float(rc.y), c5 = __int_as_float(rc.w);
        float c6 = __int_as_float(rd.y), c7 = __int_as_float(rd.w);
        acc.x += c0 * bf2f(v0.x) + c1 * bf2f(v1.x) + c2 * bf2f(v2.x) + c3 * bf2f(v3.x)
               + c4 * bf2f(v4.x) + c5 * bf2f(v5.x) + c6 * bf2f(v6.x) + c7 * bf2f(v7.x);
        acc.y += c0 * bf2f(v0.y) + c1 * bf2f(v1.y) + c2 * bf2f(v2.y) + c3 * bf2f(v3.y)
               + c4 * bf2f(v4.y) + c5 * bf2f(v5.y) + c6 * bf2f(v6.y) + c7 * bf2f(v7.y);
        acc.z += c0 * bf2f(v0.z) + c1 * bf2f(v1.z) + c2 * bf2f(v2.z) + c3 * bf2f(v3.z)
               + c4 * bf2f(v4.z) + c5 * bf2f(v5.z) + c6 * bf2f(v6.z) + c7 * bf2f(v7.z);
        acc.w += c0 * bf2f(v0.w) + c1 * bf2f(v1.w) + c2 * bf2f(v2.w) + c3 * bf2f(v3.w)
               + c4 * bf2f(v4.w) + c5 * bf2f(v5.w) + c6 * bf2f(v6.w) + c7 * bf2f(v7.w);
    }
    acc.x = acc.x >= 0.f ? acc.x : NEG_SLOPE * acc.x;
    acc.y = acc.y >= 0.f ? acc.y : NEG_SLOPE * acc.y;
    acc.z = acc.z >= 0.f ? acc.z : NEG_SLOPE * acc.z;
    acc.w = acc.w >= 0.f ? acc.w : NEG_SLOPE * acc.w;
    __hip_bfloat16 pk[4] = {__float2bfloat16(acc.x), __float2bfloat16(acc.y),
                            __float2bfloat16(acc.z), __float2bfloat16(acc.w)};
    *(uint2*)(out + (size_t)node * HIDDEN + lane * 4) = *(uint2*)pk;
}

// ---------------- global mean pool (partial sums + atomics), bf16 input ----------------
__global__ void k_pool(const __hip_bfloat16* __restrict__ h, const int* __restrict__ gstart,
                       const int* __restrict__ gcnt, float* __restrict__ pooled) {
    int g = blockIdx.x, chunk = blockIdx.y, t = threadIdx.x;
    int s = gstart[g], c = gcnt[g];
    int i0 = s + (int)(((long long)c * chunk) / 16);
    int i1 = s + (int)(((long long)c * (chunk + 1)) / 16);
    const unsigned short* hu = (const unsigned short*)h;
    float acc = 0.f;
    for (int i = i0; i < i1; ++i) acc += bf2f(hu[(size_t)i * HIDDEN + t]);
    atomicAdd(&pooled[g * HIDDEN + t], acc);
}

// ---------------- classifier head + softmax (one wave per graph) ----------------
__global__ void k_head(const float* __restrict__ pooled, const int* __restrict__ gcnt,
                       const float* __restrict__ Wc, const float* __restrict__ bc,
                       float* __restrict__ out) {
    int g = blockIdx.x; int l = threadIdx.x;  // 64 threads
    float inv = 1.0f / fmaxf((float)gcnt[g], 1.0f);
    float p[4];
#pragma unroll
    for (int i = 0; i < 4; i++) p[i] = pooled[g * HIDDEN + l + i * 64] * inv;
    __shared__ float logits[N_CLASSES];
#pragma unroll
    for (int j = 0; j < N_CLASSES; j++) {
        float s = 0.f;
#pragma unroll
        for (int i = 0; i < 4; i++) s += p[i] * Wc[(l + i * 64) * N_CLASSES + j];
        for (int o = 32; o > 0; o >>= 1) s += __shfl_down(s, o, 64);
        if (l == 0) logits[j] = s + bc[j];
    }
    __syncthreads();
    if (l == 0) {
        float m = logits[0];
        for (int j = 1; j < N_CLASSES; j++) m = fmaxf(m, logits[j]);
        float e[N_CLASSES]; float sum = 0.f;
        for (int j = 0; j < N_CLASSES; j++) { e[j] = expf(logits[j] - m); sum += e[j]; }
        for (int j = 0; j < N_CLASSES; j++) out[g * N_CLASSES + j] = e[j] / sum;
    }
}

extern "C" void kernel_launch(void* const* d_in, const int* in_sizes, int n_in,
                              void* d_out, int out_size, void* d_ws, size_t ws_size,
                              hipStream_t stream) {
    const float* x     = (const float*)d_in[0];
    const int*   edge  = (const int*)d_in[1];
    const int*   batch = (const int*)d_in[2];
    const float* W1 = (const float*)d_in[3];
    const float* b1 = (const float*)d_in[4];
    const float* W2 = (const float*)d_in[5];
    const float* b2 = (const float*)d_in[6];
    const float* W3 = (const float*)d_in[7];
    const float* b3 = (const float*)d_in[8];
    const float* Wc = (const float*)d_in[9];
    const float* bc = (const float*)d_in[10];
    float* out = (float*)d_out;
    const int* srcp = edge;
    const int* dstp = edge + N_EDGES;

    char* ws = (char*)d_ws;
    size_t off = 0;
    auto alloc = [&](size_t bytes) -> char* {
        char* p = ws + off;
        off += (bytes + 255) & ~(size_t)255;
        return p;
    };
    __hip_bfloat16* hA  = (__hip_bfloat16*)alloc((size_t)N_NODES * HIDDEN * 2);
    __hip_bfloat16* hB  = (__hip_bfloat16*)alloc((size_t)N_NODES * HIDDEN * 2);
    __hip_bfloat16* Wt2 = (__hip_bfloat16*)alloc((size_t)HIDDEN * HIDDEN * 2);
    __hip_bfloat16* Wt3 = (__hip_bfloat16*)alloc((size_t)HIDDEN * HIDDEN * 2);
    int*   deg_cnt  = (int*)alloc((size_t)N_NODES * 4);
    float* dinv     = (float*)alloc((size_t)N_NODES * 4);
    int*   csr_off  = (int*)alloc((size_t)(N_NODES + 1) * 4);
    int*   cursor   = (int*)alloc((size_t)N_NODES * 4);
    int2*  csr_rec  = (int2*)alloc((size_t)E_PAD * 8);
    float4* ax      = (float4*)alloc((size_t)N_NODES * 16);
    int*   gcnt     = (int*)alloc((size_t)N_GRAPHS * 4);
    int*   gstart   = (int*)alloc((size_t)N_GRAPHS * 4);
    float* pooled   = (float*)alloc((size_t)N_GRAPHS * HIDDEN * 4);
    int*   bsum     = (int*)alloc(128 * 4);

    hipMemsetAsync(deg_cnt, 0, (size_t)N_NODES * 4, stream);
    hipMemsetAsync(pooled, 0, (size_t)N_GRAPHS * HIDDEN * 4, stream);

    int eb4 = (N_EDGES / 4 + 255) / 256;   // 4 edges/thread
    int nb  = (N_NODES + 255) / 256;
    int sblocks = (N_NODES + 1023) / 1024;  // 98
    int fillb = N_RANGES * ((N_EDGES + CHUNK - 1) / CHUNK);  // 8 x 782

    k_deg_hist<<<eb4, 256, 0, stream>>>(dstp, deg_cnt);
    k_graph_bounds<<<1, 64, 0, stream>>>(batch, gstart, gcnt);
    k_dinv<<<nb, 256, 0, stream>>>(deg_cnt, dinv);
    k_scanA<<<sblocks, 256, 0, stream>>>(deg_cnt, csr_off, bsum);
    k_scanB<<<1, 128, 0, stream>>>(bsum, sblocks);
    k_scanC<<<nb, 256, 0, stream>>>(csr_off, bsum, cursor, deg_cnt, csr_rec);
    k_fill<<<fillb, 256, 0, stream>>>(srcp, dstp, dinv, cursor, csr_rec);
    k_wprep<<<HIDDEN, HIDDEN, 0, stream>>>(W2, Wt2);
    k_wprep<<<HIDDEN, HIDDEN, 0, stream>>>(W3, Wt3);

    // layer 1 (reassociated): ax = Norm*x; h1 = leaky(ax @ W1 + b1)
    k_agg3<<<nb, 256, 0, stream>>>(x, csr_off, csr_rec, dinv, ax);
    k_l1<<<N_NODES, 256, 0, stream>>>(ax, W1, b1, hA);

    int aggb  = (N_NODES + 3) / 4;
    int gemmb = (N_NODES + 63) / 64;
    // layer 2
    k_gemm_mfma<<<gemmb, 256, 0, stream>>>(hA, Wt2, hB, N_NODES);
    k_agg<<<aggb, 256, 0, stream>>>(hB, b2, csr_off, csr_rec, dinv, hA);
    // layer 3
    k_gemm_mfma<<<gemmb, 256, 0, stream>>>(hA, Wt3, hB, N_NODES);
    k_agg<<<aggb, 256, 0, stream>>>(hB, b3, csr_off, csr_rec, dinv, hA);
    // pool + head
    dim3 pg(N_GRAPHS, 16);
    k_pool<<<pg, 256, 0, stream>>>(hA, gstart, gcnt, pooled);
    k_head<<<N_GRAPHS, 64, 0, stream>>>(pooled, gcnt, Wc, bc, out);
}

// Round 11
// 631.764 us; speedup vs baseline: 1.3697x; 1.1706x over previous
//
#include <hip/hip_runtime.h>
#include <hip/hip_bf16.h>
#include <cstdint>
#include <cstddef>

#define N_NODES   100000
#define N_EDGES   1600000
#define N_GRAPHS  64
#define HIDDEN    256
#define N_CLASSES 10
#define NEG_SLOPE 0.01f

#define E_PAD    (N_EDGES + 8 * N_NODES)
#define N_RANGES 8
#define R_SIZE   ((N_NODES + N_RANGES - 1) / N_RANGES)   // 12500
#define CHUNK    2048

typedef __attribute__((ext_vector_type(8))) short bfrag8;   // 8 bf16 (4 VGPRs)
typedef __attribute__((ext_vector_type(4))) float f32x4;    // MFMA C/D
typedef __attribute__((ext_vector_type(2))) float f32x2;

__device__ __forceinline__ float bf2f(unsigned short u) {
    return __uint_as_float(((unsigned int)u) << 16);
}

// pack one float -> fp8 e4m3 byte (HW cvt)
__device__ __forceinline__ unsigned char f2fp8(float v) {
    return (unsigned char)(__builtin_amdgcn_cvt_pk_fp8_f32(v, v, 0, false) & 0xff);
}

// ---------------- degree histogram (4 edges/thread) ----------------
__global__ void k_deg_hist(const int* __restrict__ dst, int* __restrict__ cnt) {
    int e = (blockIdx.x * 256 + threadIdx.x) * 4;
    if (e >= N_EDGES) return;
    int4 d4 = *(const int4*)(dst + e);
    atomicAdd(&cnt[d4.x], 1);
    atomicAdd(&cnt[d4.y], 1);
    atomicAdd(&cnt[d4.z], 1);
    atomicAdd(&cnt[d4.w], 1);
}

// ---------------- graph boundaries via binary search (batch is sorted) ----------------
__global__ void k_graph_bounds(const int* __restrict__ batch,
                               int* __restrict__ gstart, int* __restrict__ gcnt) {
    int g = threadIdx.x;  // 0..63
    int lo = 0, hi = N_NODES;
    while (lo < hi) { int mid = (lo + hi) >> 1; if (batch[mid] < g) lo = mid + 1; else hi = mid; }
    __shared__ int sh[N_GRAPHS + 1];
    sh[g] = lo;
    if (g == 0) sh[N_GRAPHS] = N_NODES;
    __syncthreads();
    gstart[g] = sh[g];
    gcnt[g]   = sh[g + 1] - sh[g];
}

__global__ void k_dinv(const int* __restrict__ cnt, float* __restrict__ dinv) {
    int i = blockIdx.x * 256 + threadIdx.x;
    if (i < N_NODES) dinv[i] = rsqrtf((float)cnt[i] + 1.0f);
}

// ---------------- exclusive scan of PADDED degree counts (CSR offsets) ----------------
__global__ void k_scanA(const int* __restrict__ cnt, int* __restrict__ out, int* __restrict__ bsum) {
    __shared__ int sh[256];
    int tid = threadIdx.x;
    int base = blockIdx.x * 1024 + tid * 4;
    int v[4]; int s = 0;
#pragma unroll
    for (int i = 0; i < 4; i++) {
        int idx = base + i;
        v[i] = (idx < N_NODES) ? ((cnt[idx] + 7) & ~7) : 0;
        s += v[i];
    }
    sh[tid] = s; __syncthreads();
    for (int off = 1; off < 256; off <<= 1) {
        int t = (tid >= off) ? sh[tid - off] : 0;
        __syncthreads();
        sh[tid] += t;
        __syncthreads();
    }
    int excl = sh[tid] - s;
    if (tid == 255) bsum[blockIdx.x] = sh[255];
#pragma unroll
    for (int i = 0; i < 4; i++) { int idx = base + i; if (idx < N_NODES) out[idx] = excl; excl += v[i]; }
}

__global__ void k_scanB(int* __restrict__ bsum, int nb) {
    __shared__ int sh[128];
    int tid = threadIdx.x;
    int v = (tid < nb) ? bsum[tid] : 0;
    sh[tid] = v; __syncthreads();
    for (int off = 1; off < 128; off <<= 1) {
        int t = (tid >= off) ? sh[tid - off] : 0;
        __syncthreads();
        sh[tid] += t;
        __syncthreads();
    }
    if (tid < nb) bsum[tid] = sh[tid] - v;  // exclusive
}

// finalize offsets + init cursor + final {0,0.0} records into padding slots
__global__ void k_scanC(int* __restrict__ off_arr, const int* __restrict__ bsum,
                        int* __restrict__ cursor, const int* __restrict__ cnt,
                        int2* __restrict__ rec) {
    int i = blockIdx.x * 256 + threadIdx.x;
    if (i < N_NODES) {
        int v = off_arr[i] + bsum[i >> 10];
        off_arr[i] = v;
        cursor[i]  = v;
        int c  = cnt[i];
        int cp = (c + 7) & ~7;
        for (int p = v + c; p < v + cp; ++p) rec[p] = make_int2(0, 0);
        if (i == N_NODES - 1) off_arr[N_NODES] = v + cp;
    }
}

// ---------------- XCD-partitioned CSR fill, coef fused ----------------
__global__ __launch_bounds__(256) void k_fill(const int* __restrict__ src, const int* __restrict__ dst,
                                              const float* __restrict__ dinv,
                                              int* __restrict__ cursor, int2* __restrict__ rec) {
    int b = blockIdx.x;
    int r = b & (N_RANGES - 1);
    int lo = r * R_SIZE, hi = lo + R_SIZE;
    int e0 = (b >> 3) * CHUNK + threadIdx.x * 8;
    if (e0 >= N_EDGES) return;
    if (e0 + 8 <= N_EDGES) {
        int4 da = *(const int4*)(dst + e0);
        int4 db = *(const int4*)(dst + e0 + 4);
        int d[8] = {da.x, da.y, da.z, da.w, db.x, db.y, db.z, db.w};
#pragma unroll
        for (int j = 0; j < 8; ++j) {
            if (d[j] >= lo && d[j] < hi) {
                int s = src[e0 + j];
                float c = dinv[s] * dinv[d[j]];
                int p = atomicAdd(&cursor[d[j]], 1);
                rec[p] = make_int2(s, __float_as_int(c));
            }
        }
    } else {
        for (int j = 0; j < 8 && e0 + j < N_EDGES; ++j) {
            int dj = dst[e0 + j];
            if (dj >= lo && dj < hi) {
                int s = src[e0 + j];
                float c = dinv[s] * dinv[dj];
                int p = atomicAdd(&cursor[dj], 1);
                rec[p] = make_int2(s, __float_as_int(c));
            }
        }
    }
}

// ---------------- weight prep: W[k][n] fp32 -> Wt[n][k] bf16 ----------------
__global__ void k_wprep(const float* __restrict__ W, __hip_bfloat16* __restrict__ Wt) {
    int n = blockIdx.x; int k = threadIdx.x;  // 256 x 256
    Wt[n * HIDDEN + k] = __float2bfloat16(W[k * HIDDEN + n]);
}

// ---------------- layer-1 reassociated: ax = Norm * x  (3 features, exact) ----------------
__global__ void k_agg3(const float* __restrict__ x, const int* __restrict__ off,
                       const int2* __restrict__ rec, const float* __restrict__ dinv,
                       float4* __restrict__ ax) {
    int i = blockIdx.x * 256 + threadIdx.x;
    if (i >= N_NODES) return;
    float di = dinv[i];
    float selfc = di * di;
    float a0 = x[i * 3 + 0] * selfc, a1 = x[i * 3 + 1] * selfc, a2 = x[i * 3 + 2] * selfc;
    int e = off[i], e1 = off[i + 1];
    for (; e < e1; e += 4) {
        const int4* rp = (const int4*)(rec + e);
        int4 r01 = rp[0];  // {s0, c0, s1, c1}
        int4 r23 = rp[1];  // {s2, c2, s3, c3}
        int s0 = r01.x, s1 = r01.z, s2 = r23.x, s3 = r23.z;
        float c0 = __int_as_float(r01.y), c1 = __int_as_float(r01.w);
        float c2 = __int_as_float(r23.y), c3 = __int_as_float(r23.w);
        a0 += c0 * x[s0 * 3 + 0] + c1 * x[s1 * 3 + 0] + c2 * x[s2 * 3 + 0] + c3 * x[s3 * 3 + 0];
        a1 += c0 * x[s0 * 3 + 1] + c1 * x[s1 * 3 + 1] + c2 * x[s2 * 3 + 1] + c3 * x[s3 * 3 + 1];
        a2 += c0 * x[s0 * 3 + 2] + c1 * x[s1 * 3 + 2] + c2 * x[s2 * 3 + 2] + c3 * x[s3 * 3 + 2];
    }
    ax[i] = make_float4(a0, a1, a2, 0.f);
}

// h1 = leaky(ax @ W1 + b1), bf16 out (hA, linear-read by GEMM)
__global__ void k_l1(const float4* __restrict__ ax, const float* __restrict__ W1,
                     const float* __restrict__ b1, __hip_bfloat16* __restrict__ out) {
    int node = blockIdx.x; int c = threadIdx.x;
    float4 a = ax[node];
    float v = a.x * W1[c] + a.y * W1[HIDDEN + c] + a.z * W1[2 * HIDDEN + c] + b1[c];
    v = v >= 0.f ? v : NEG_SLOPE * v;
    out[(size_t)node * HIDDEN + c] = __float2bfloat16(v);
}

// ---------------- MFMA GEMM with LDS-staged Wt; C stored as fp8 e4m3 ----------------
__global__ __launch_bounds__(256) void k_gemm_mfma(const __hip_bfloat16* __restrict__ A,
                                                   const __hip_bfloat16* __restrict__ Wt,
                                                   unsigned char* __restrict__ C, int M) {
    __shared__ short Bs[256 * 40];  // 20 KB
    int tid = threadIdx.x;
    int wv = tid >> 6, lane = tid & 63;
    int quad = lane >> 4, r = lane & 15;
    int m0 = blockIdx.x * 64 + wv * 16;
    int arow = m0 + r; if (arow >= M) arow = M - 1;
    const short* Ab = (const short*)A + (size_t)arow * HIDDEN + quad * 8;

    bfrag8 af[8];
#pragma unroll
    for (int c = 0; c < 8; ++c) af[c] = *(const bfrag8*)(Ab + c * 32);

    f32x4 acc[16];
#pragma unroll
    for (int i = 0; i < 16; i++) acc[i] = (f32x4){0.f, 0.f, 0.f, 0.f};

    const float4* wsrc = (const float4*)((const short*)Wt + (size_t)tid * HIDDEN);  // row n=tid
    float4 st[4];
#pragma unroll
    for (int i = 0; i < 4; ++i) st[i] = wsrc[i];  // chunk 0

#pragma unroll
    for (int c = 0; c < 8; ++c) {
        __syncthreads();
        float4* bdst = (float4*)(Bs + tid * 40);
#pragma unroll
        for (int i = 0; i < 4; ++i) bdst[i] = st[i];
        __syncthreads();
        if (c < 7) {
#pragma unroll
            for (int i = 0; i < 4; ++i) st[i] = wsrc[(c + 1) * 4 + i];
        }
#pragma unroll
        for (int nt = 0; nt < 16; ++nt) {
            bfrag8 b = *(const bfrag8*)(Bs + (nt * 16 + r) * 40 + quad * 8);
            acc[nt] = __builtin_amdgcn_mfma_f32_16x16x32_bf16(af[c], b, acc[nt], 0, 0, 0);
        }
    }
#pragma unroll
    for (int nt = 0; nt < 16; ++nt) {
#pragma unroll
        for (int i = 0; i < 4; ++i) {
            int row = m0 + quad * 4 + i;
            if (row < M) C[(size_t)row * HIDDEN + nt * 16 + r] = f2fp8(acc[nt][i]);
        }
    }
}

// ---------------- fused aggregation + self-loop + bias + leaky-relu ----------------
// one wave per node; h rows are fp8 (256 B); lane = 4 fp8 bytes; 8 gathers in flight
__global__ __launch_bounds__(256) void k_agg(const unsigned char* __restrict__ h,
                                             const float* __restrict__ bias,
                                             const int* __restrict__ off, const int2* __restrict__ rec,
                                             const float* __restrict__ dinv,
                                             __hip_bfloat16* __restrict__ out) {
    int node = (blockIdx.x * 256 + threadIdx.x) >> 6;
    int lane = threadIdx.x & 63;
    if (node >= N_NODES) return;
    float di = dinv[node];
    float selfc = di * di;
    unsigned int hv = *(const unsigned int*)(h + (size_t)node * HIDDEN + lane * 4);
    f32x2 hlo = __builtin_amdgcn_cvt_pk_f32_fp8(hv, false);
    f32x2 hhi = __builtin_amdgcn_cvt_pk_f32_fp8(hv, true);
    float4 bv = ((const float4*)bias)[lane];
    float4 acc = make_float4(bv.x + hlo.x * selfc, bv.y + hlo.y * selfc,
                             bv.z + hhi.x * selfc, bv.w + hhi.y * selfc);
    int e = off[node], e1 = off[node + 1];
    for (; e < e1; e += 8) {
        const int4* rp = (const int4*)(rec + e);
        int4 ra = rp[0];  // {s0,c0,s1,c1}
        int4 rb = rp[1];  // {s2,c2,s3,c3}
        int4 rc = rp[2];  // {s4,c4,s5,c5}
        int4 rd = rp[3];  // {s6,c6,s7,c7}
        unsigned int w0 = *(const unsigned int*)(h + (size_t)ra.x * HIDDEN + lane * 4);
        unsigned int w1 = *(const unsigned int*)(h + (size_t)ra.z * HIDDEN + lane * 4);
        unsigned int w2 = *(const unsigned int*)(h + (size_t)rb.x * HIDDEN + lane * 4);
        unsigned int w3 = *(const unsigned int*)(h + (size_t)rb.z * HIDDEN + lane * 4);
        unsigned int w4 = *(const unsigned int*)(h + (size_t)rc.x * HIDDEN + lane * 4);
        unsigned int w5 = *(const unsigned int*)(h + (size_t)rc.z * HIDDEN + lane * 4);
        unsigned int w6 = *(const unsigned int*)(h + (size_t)rd.x * HIDDEN + lane * 4);
        unsigned int w7 = *(const unsigned int*)(h + (size_t)rd.z * HIDDEN + lane * 4);
        float c0 = __int_as_float(ra.y), c1 = __int_as_float(ra.w);
        float c2 = __int_as_float(rb.y), c3 = __int_as_float(rb.w);
        float c4 = __int_as_float(rc.y), c5 = __int_as_float(rc.w);
        float c6 = __int_as_float(rd.y), c7 = __int_as_float(rd.w);
        f32x2 l0 = __builtin_amdgcn_cvt_pk_f32_fp8(w0, false), g0 = __builtin_amdgcn_cvt_pk_f32_fp8(w0, true);
        f32x2 l1 = __builtin_amdgcn_cvt_pk_f32_fp8(w1, false), g1 = __builtin_amdgcn_cvt_pk_f32_fp8(w1, true);
        f32x2 l2 = __builtin_amdgcn_cvt_pk_f32_fp8(w2, false), g2 = __builtin_amdgcn_cvt_pk_f32_fp8(w2, true);
        f32x2 l3 = __builtin_amdgcn_cvt_pk_f32_fp8(w3, false), g3 = __builtin_amdgcn_cvt_pk_f32_fp8(w3, true);
        f32x2 l4 = __builtin_amdgcn_cvt_pk_f32_fp8(w4, false), g4 = __builtin_amdgcn_cvt_pk_f32_fp8(w4, true);
        f32x2 l5 = __builtin_amdgcn_cvt_pk_f32_fp8(w5, false), g5 = __builtin_amdgcn_cvt_pk_f32_fp8(w5, true);
        f32x2 l6 = __builtin_amdgcn_cvt_pk_f32_fp8(w6, false), g6 = __builtin_amdgcn_cvt_pk_f32_fp8(w6, true);
        f32x2 l7 = __builtin_amdgcn_cvt_pk_f32_fp8(w7, false), g7 = __builtin_amdgcn_cvt_pk_f32_fp8(w7, true);
        acc.x += c0 * l0.x + c1 * l1.x + c2 * l2.x + c3 * l3.x
               + c4 * l4.x + c5 * l5.x + c6 * l6.x + c7 * l7.x;
        acc.y += c0 * l0.y + c1 * l1.y + c2 * l2.y + c3 * l3.y
               + c4 * l4.y + c5 * l5.y + c6 * l6.y + c7 * l7.y;
        acc.z += c0 * g0.x + c1 * g1.x + c2 * g2.x + c3 * g3.x
               + c4 * g4.x + c5 * g5.x + c6 * g6.x + c7 * g7.x;
        acc.w += c0 * g0.y + c1 * g1.y + c2 * g2.y + c3 * g3.y
               + c4 * g4.y + c5 * g5.y + c6 * g6.y + c7 * g7.y;
    }
    acc.x = acc.x >= 0.f ? acc.x : NEG_SLOPE * acc.x;
    acc.y = acc.y >= 0.f ? acc.y : NEG_SLOPE * acc.y;
    acc.z = acc.z >= 0.f ? acc.z : NEG_SLOPE * acc.z;
    acc.w = acc.w >= 0.f ? acc.w : NEG_SLOPE * acc.w;
    __hip_bfloat16 pk[4] = {__float2bfloat16(acc.x), __float2bfloat16(acc.y),
                            __float2bfloat16(acc.z), __float2bfloat16(acc.w)};
    *(uint2*)(out + (size_t)node * HIDDEN + lane * 4) = *(uint2*)pk;
}

// ---------------- global mean pool (partial sums + atomics), bf16 input ----------------
__global__ void k_pool(const __hip_bfloat16* __restrict__ h, const int* __restrict__ gstart,
                       const int* __restrict__ gcnt, float* __restrict__ pooled) {
    int g = blockIdx.x, chunk = blockIdx.y, t = threadIdx.x;
    int s = gstart[g], c = gcnt[g];
    int i0 = s + (int)(((long long)c * chunk) / 16);
    int i1 = s + (int)(((long long)c * (chunk + 1)) / 16);
    const unsigned short* hu = (const unsigned short*)h;
    float acc = 0.f;
    for (int i = i0; i < i1; ++i) acc += bf2f(hu[(size_t)i * HIDDEN + t]);
    atomicAdd(&pooled[g * HIDDEN + t], acc);
}

// ---------------- classifier head + softmax (one wave per graph) ----------------
__global__ void k_head(const float* __restrict__ pooled, const int* __restrict__ gcnt,
                       const float* __restrict__ Wc, const float* __restrict__ bc,
                       float* __restrict__ out) {
    int g = blockIdx.x; int l = threadIdx.x;  // 64 threads
    float inv = 1.0f / fmaxf((float)gcnt[g], 1.0f);
    float p[4];
#pragma unroll
    for (int i = 0; i < 4; i++) p[i] = pooled[g * HIDDEN + l + i * 64] * inv;
    __shared__ float logits[N_CLASSES];
#pragma unroll
    for (int j = 0; j < N_CLASSES; j++) {
        float s = 0.f;
#pragma unroll
        for (int i = 0; i < 4; i++) s += p[i] * Wc[(l + i * 64) * N_CLASSES + j];
        for (int o = 32; o > 0; o >>= 1) s += __shfl_down(s, o, 64);
        if (l == 0) logits[j] = s + bc[j];
    }
    __syncthreads();
    if (l == 0) {
        float m = logits[0];
        for (int j = 1; j < N_CLASSES; j++) m = fmaxf(m, logits[j]);
        float e[N_CLASSES]; float sum = 0.f;
        for (int j = 0; j < N_CLASSES; j++) { e[j] = expf(logits[j] - m); sum += e[j]; }
        for (int j = 0; j < N_CLASSES; j++) out[g * N_CLASSES + j] = e[j] / sum;
    }
}

extern "C" void kernel_launch(void* const* d_in, const int* in_sizes, int n_in,
                              void* d_out, int out_size, void* d_ws, size_t ws_size,
                              hipStream_t stream) {
    const float* x     = (const float*)d_in[0];
    const int*   edge  = (const int*)d_in[1];
    const int*   batch = (const int*)d_in[2];
    const float* W1 = (const float*)d_in[3];
    const float* b1 = (const float*)d_in[4];
    const float* W2 = (const float*)d_in[5];
    const float* b2 = (const float*)d_in[6];
    const float* W3 = (const float*)d_in[7];
    const float* b3 = (const float*)d_in[8];
    const float* Wc = (const float*)d_in[9];
    const float* bc = (const float*)d_in[10];
    float* out = (float*)d_out;
    const int* srcp = edge;
    const int* dstp = edge + N_EDGES;

    char* ws = (char*)d_ws;
    size_t off = 0;
    auto alloc = [&](size_t bytes) -> char* {
        char* p = ws + off;
        off += (bytes + 255) & ~(size_t)255;
        return p;
    };
    __hip_bfloat16* hA = (__hip_bfloat16*)alloc((size_t)N_NODES * HIDDEN * 2);  // agg/l1 out (GEMM in, linear)
    unsigned char*  hB = (unsigned char*)alloc((size_t)N_NODES * HIDDEN);       // GEMM out fp8 (gathered)
    __hip_bfloat16* Wt2 = (__hip_bfloat16*)alloc((size_t)HIDDEN * HIDDEN * 2);
    __hip_bfloat16* Wt3 = (__hip_bfloat16*)alloc((size_t)HIDDEN * HIDDEN * 2);
    int*   deg_cnt  = (int*)alloc((size_t)N_NODES * 4);
    float* dinv     = (float*)alloc((size_t)N_NODES * 4);
    int*   csr_off  = (int*)alloc((size_t)(N_NODES + 1) * 4);
    int*   cursor   = (int*)alloc((size_t)N_NODES * 4);
    int2*  csr_rec  = (int2*)alloc((size_t)E_PAD * 8);
    float4* ax      = (float4*)alloc((size_t)N_NODES * 16);
    int*   gcnt     = (int*)alloc((size_t)N_GRAPHS * 4);
    int*   gstart   = (int*)alloc((size_t)N_GRAPHS * 4);
    float* pooled   = (float*)alloc((size_t)N_GRAPHS * HIDDEN * 4);
    int*   bsum     = (int*)alloc(128 * 4);

    hipMemsetAsync(deg_cnt, 0, (size_t)N_NODES * 4, stream);
    hipMemsetAsync(pooled, 0, (size_t)N_GRAPHS * HIDDEN * 4, stream);

    int eb4 = (N_EDGES / 4 + 255) / 256;   // 4 edges/thread
    int nb  = (N_NODES + 255) / 256;
    int sblocks = (N_NODES + 1023) / 1024;  // 98
    int fillb = N_RANGES * ((N_EDGES + CHUNK - 1) / CHUNK);  // 8 x 782

    k_deg_hist<<<eb4, 256, 0, stream>>>(dstp, deg_cnt);
    k_graph_bounds<<<1, 64, 0, stream>>>(batch, gstart, gcnt);
    k_dinv<<<nb, 256, 0, stream>>>(deg_cnt, dinv);
    k_scanA<<<sblocks, 256, 0, stream>>>(deg_cnt, csr_off, bsum);
    k_scanB<<<1, 128, 0, stream>>>(bsum, sblocks);
    k_scanC<<<nb, 256, 0, stream>>>(csr_off, bsum, cursor, deg_cnt, csr_rec);
    k_fill<<<fillb, 256, 0, stream>>>(srcp, dstp, dinv, cursor, csr_rec);
    k_wprep<<<HIDDEN, HIDDEN, 0, stream>>>(W2, Wt2);
    k_wprep<<<HIDDEN, HIDDEN, 0, stream>>>(W3, Wt3);

    // layer 1 (reassociated): ax = Norm*x; h1 = leaky(ax @ W1 + b1) -> hA (bf16)
    k_agg3<<<nb, 256, 0, stream>>>(x, csr_off, csr_rec, dinv, ax);
    k_l1<<<N_NODES, 256, 0, stream>>>(ax, W1, b1, hA);

    int aggb  = (N_NODES + 3) / 4;
    int gemmb = (N_NODES + 63) / 64;
    // layer 2
    k_gemm_mfma<<<gemmb, 256, 0, stream>>>(hA, Wt2, hB, N_NODES);
    k_agg<<<aggb, 256, 0, stream>>>(hB, b2, csr_off, csr_rec, dinv, hA);
    // layer 3
    k_gemm_mfma<<<gemmb, 256, 0, stream>>>(hA, Wt3, hB, N_NODES);
    k_agg<<<aggb, 256, 0, stream>>>(hB, b3, csr_off, csr_rec, dinv, hA);
    // pool + head
    dim3 pg(N_GRAPHS, 16);
    k_pool<<<pg, 256, 0, stream>>>(hA, gstart, gcnt, pooled);
    k_head<<<N_GRAPHS, 64, 0, stream>>>(pooled, gcnt, Wc, bc, out);
}